// Round 1
// baseline (3210.146 us; speedup 1.0000x reference)
//
#include <hip/hip_runtime.h>
#include <cstdint>
#include <cstddef>

#define LSEQ 2048
#define NB   4
#define DMODEL 1024
#define DINNER 2048
#define NST  16

__device__ __forceinline__ float siluf(float x) { return x / (1.f + __expf(-x)); }

// ---------------- RMSNorm row inverse-scale ----------------
__global__ __launch_bounds__(256) void rms_inv_k(const float* __restrict__ x,
                                                 float* __restrict__ inv) {
    int row = blockIdx.x;
    float4 v = ((const float4*)(x + (size_t)row * DMODEL))[threadIdx.x];
    float s = v.x * v.x + v.y * v.y + v.z * v.z + v.w * v.w;
#pragma unroll
    for (int m = 32; m >= 1; m >>= 1) s += __shfl_xor(s, m);
    __shared__ float wsum[4];
    if ((threadIdx.x & 63) == 0) wsum[threadIdx.x >> 6] = s;
    __syncthreads();
    if (threadIdx.x == 0) {
        float tot = wsum[0] + wsum[1] + wsum[2] + wsum[3];
        inv[row] = rsqrtf(tot * (1.f / (float)DMODEL) + 1e-6f);
    }
}

// ---------------- Generic NT GEMM: C = A(MxK,lda) * W(NxK)^T ----------------
// EPI 0: plain store
// EPI 1: softplus(acc + bias[col]) * mask(row)
// EPI 2: residual[row,col] + mask(row) * acc
template <int EPI, bool NORMA>
__global__ __launch_bounds__(256) void gemm_nt(
    const float* __restrict__ A, int lda,
    const float* __restrict__ W,
    float* __restrict__ C, int ldc,
    int M, int N, int K,
    const float* __restrict__ rowscale,   // NORMA: per-row rms inv
    const float* __restrict__ kscale,     // NORMA: norm_w
    const float* __restrict__ bias,       // EPI==1
    const float* __restrict__ residual,   // EPI==2
    const int* __restrict__ lengths) {
    __shared__ float As[16][68];
    __shared__ float Ws[16][68];
    const int t = threadIdx.x;
    const int row0 = blockIdx.y * 64;
    const int col0 = blockIdx.x * 64;
    const int lm = t >> 2;          // 0..63
    const int lk = (t & 3) << 2;    // 0,4,8,12
    const int tx = t & 15, ty = t >> 4;
    const int arow = row0 + lm;
    const int wcol = col0 + lm;
    float rs = NORMA ? rowscale[arow] : 1.f;
    float acc[4][4] = {};
    for (int k0 = 0; k0 < K; k0 += 16) {
        float4 av = *(const float4*)(A + (size_t)arow * lda + k0 + lk);
        if (NORMA) {
            float4 nw = *(const float4*)(kscale + k0 + lk);
            av.x *= rs * nw.x; av.y *= rs * nw.y;
            av.z *= rs * nw.z; av.w *= rs * nw.w;
        }
        As[lk + 0][lm] = av.x; As[lk + 1][lm] = av.y;
        As[lk + 2][lm] = av.z; As[lk + 3][lm] = av.w;
        float4 wv = make_float4(0.f, 0.f, 0.f, 0.f);
        if (wcol < N) wv = *(const float4*)(W + (size_t)wcol * K + k0 + lk);
        Ws[lk + 0][lm] = wv.x; Ws[lk + 1][lm] = wv.y;
        Ws[lk + 2][lm] = wv.z; Ws[lk + 3][lm] = wv.w;
        __syncthreads();
#pragma unroll
        for (int kk = 0; kk < 16; ++kk) {
            float a_[4], b_[4];
#pragma unroll
            for (int i = 0; i < 4; ++i) a_[i] = As[kk][ty * 4 + i];
#pragma unroll
            for (int j = 0; j < 4; ++j) b_[j] = Ws[kk][tx * 4 + j];
#pragma unroll
            for (int i = 0; i < 4; ++i)
#pragma unroll
                for (int j = 0; j < 4; ++j)
                    acc[i][j] = fmaf(a_[i], b_[j], acc[i][j]);
        }
        __syncthreads();
    }
#pragma unroll
    for (int i = 0; i < 4; ++i) {
        int row = row0 + ty * 4 + i;
        float msk = 1.f;
        if (EPI != 0) {
            int b = row >> 11, l = row & (LSEQ - 1);
            msk = (l < lengths[b]) ? 1.f : 0.f;
        }
#pragma unroll
        for (int j = 0; j < 4; ++j) {
            int col = col0 + tx * 4 + j;
            if (col < N) {
                float v = acc[i][j];
                if (EPI == 1) {
                    v += bias[col];
                    v = (v > 20.f) ? v : log1pf(expf(v));
                    v *= msk;
                } else if (EPI == 2) {
                    v = residual[(size_t)row * N + col] + msk * v;
                }
                C[(size_t)row * ldc + col] = v;
            }
        }
    }
}

// ---------------- causal depthwise conv (K=4) + SiLU + mask ----------------
// reads u_raw = xz[:, 0:2048] (stride 4096), masked on read; writes u (stride 2048)
__global__ __launch_bounds__(256) void conv_silu_k(const float* __restrict__ xz,
                                                   const float* __restrict__ cw,
                                                   const int* __restrict__ lengths,
                                                   float* __restrict__ u) {
    int row = blockIdx.x;               // b*L + l
    int b = row >> 11, l = row & (LSEQ - 1);
    int len = lengths[b];
    bool act = l < len;
    for (int d = threadIdx.x; d < DINNER; d += 256) {
        float4 w = *(const float4*)(cw + 4 * d);
        float wk[4] = {w.x, w.y, w.z, w.w};
        float acc = 0.f;
        int lp = l - 3;
#pragma unroll
        for (int k = 0; k < 4; ++k, ++lp) {
            if (lp >= 0 && lp < len)
                acc = fmaf(wk[k], xz[((size_t)(b * LSEQ + lp)) * 4096 + d], acc);
        }
        u[(size_t)row * DINNER + d] = act ? siluf(acc) : 0.f;
    }
}

// ---------------- selective scan ----------------
// thread layout: 16 lanes (n) per channel, 16 channels per block
__global__ __launch_bounds__(256) void scan_k(const float* __restrict__ xz,  // delta cols 0..2047, z cols 2048..4095
                                              float* u_y,                    // u in, y out (in-place)
                                              const float* __restrict__ xdbl,// (8192,96): B at 64.., C at 80..
                                              const float* __restrict__ A_log,
                                              const float* __restrict__ D_skip,
                                              float* __restrict__ out_h) {
    int t = threadIdx.x;
    int n = t & 15, ch = t >> 4;
    int b = blockIdx.x >> 7;
    int d = ((blockIdx.x & 127) << 4) + ch;
    float Av = -expf(A_log[d * NST + n]);
    float Dv = D_skip[d];
    float h = 0.f;
    for (int l = 0; l < LSEQ; ++l) {
        size_t row = (size_t)(b * LSEQ + l);
        float dl = xz[row * 4096 + d];
        float ul = u_y[row * DINNER + d];
        float Bn = xdbl[row * 96 + 64 + n];
        float Cn = xdbl[row * 96 + 80 + n];
        float dA = __expf(dl * Av);
        h = dA * h + (dl * ul) * Bn;
        float p = h * Cn;
        p += __shfl_xor(p, 1);
        p += __shfl_xor(p, 2);
        p += __shfl_xor(p, 4);
        p += __shfl_xor(p, 8);
        if (n == 0) {
            float zv = xz[row * 4096 + DINNER + d];
            u_y[row * DINNER + d] = (p + ul * Dv) * siluf(zv);
        }
    }
    out_h[((size_t)(b * DINNER + d)) * NST + n] = h;
}

extern "C" void kernel_launch(void* const* d_in, const int* in_sizes, int n_in,
                              void* d_out, int out_size, void* d_ws, size_t ws_size,
                              hipStream_t stream) {
    const float* hs        = (const float*)d_in[0];
    const int*   lengths   = (const int*)d_in[1];
    const float* norm_w    = (const float*)d_in[2];
    const float* in_proj_w = (const float*)d_in[3];
    const float* conv_w    = (const float*)d_in[4];
    const float* x_proj_w  = (const float*)d_in[5];
    const float* dt_proj_w = (const float*)d_in[6];
    const float* dt_proj_b = (const float*)d_in[7];
    const float* A_log     = (const float*)d_in[8];
    const float* D_skip    = (const float*)d_in[9];
    const float* out_proj_w= (const float*)d_in[10];

    float* out = (float*)d_out;
    float* ws  = (float*)d_ws;

    const int M = NB * LSEQ;                 // 8192
    float* inv  = ws;                        // 8192 floats
    float* xz   = inv + 8192;                // 8192 x 4096
    float* u    = xz + (size_t)M * 4096;     // 8192 x 2048 (becomes y in-place)
    float* xdbl = u + (size_t)M * DINNER;    // 8192 x 96

    // 1. RMSNorm row scales
    rms_inv_k<<<M, 256, 0, stream>>>(hs, inv);

    // 2. in_proj: xz = rmsnorm(x) @ in_proj_w^T   (8192 x 4096, K=1024)
    {
        dim3 g(4096 / 64, M / 64);
        gemm_nt<0, true><<<g, 256, 0, stream>>>(hs, DMODEL, in_proj_w, xz, 4096,
                                                M, 4096, DMODEL,
                                                inv, norm_w, nullptr, nullptr, nullptr);
    }

    // 3. causal depthwise conv + silu + mask: u
    conv_silu_k<<<M, 256, 0, stream>>>(xz, conv_w, lengths, u);

    // 4. x_proj: xdbl = u @ x_proj_w^T  (8192 x 96, K=2048)
    {
        dim3 g((96 + 63) / 64, M / 64);
        gemm_nt<0, false><<<g, 256, 0, stream>>>(u, DINNER, x_proj_w, xdbl, 96,
                                                 M, 96, DINNER,
                                                 nullptr, nullptr, nullptr, nullptr, nullptr);
    }

    // 5. dt_proj + softplus + mask: delta -> xz cols 0..2047 (u_raw half is dead)
    {
        dim3 g(DINNER / 64, M / 64);
        gemm_nt<1, false><<<g, 256, 0, stream>>>(xdbl, 96, dt_proj_w, xz, 4096,
                                                 M, DINNER, 64,
                                                 nullptr, nullptr, dt_proj_b, nullptr, lengths);
    }

    // 6. selective scan: y (in-place over u), h_last -> tail of d_out
    {
        float* hlast = out + (size_t)M * DMODEL;
        scan_k<<<NB * (DINNER / 16), 256, 0, stream>>>(xz, u, xdbl, A_log, D_skip, hlast);
    }

    // 7. out_proj + residual + mask -> d_out
    {
        dim3 g(DMODEL / 64, M / 64);
        gemm_nt<2, false><<<g, 256, 0, stream>>>(u, DINNER, out_proj_w, out, DMODEL,
                                                 M, DMODEL, DINNER,
                                                 nullptr, nullptr, nullptr, hs, lengths);
    }
}

// Round 2
// 1845.426 us; speedup vs baseline: 1.7395x; 1.7395x over previous
//
#include <hip/hip_runtime.h>
#include <cstdint>
#include <cstddef>

#define LSEQ 2048
#define NB   4
#define DMODEL 1024
#define DINNER 2048
#define NST  16
#define TT   64   // scan time-tile

__device__ __forceinline__ float siluf(float x) { return x / (1.f + __expf(-x)); }

// DPP row-rotate (within 16-lane row) for cross-lane reduce: ctrl 0x120|n = row_ror:n
template <int CTRL>
__device__ __forceinline__ float dpp_ror(float v) {
    return __int_as_float(__builtin_amdgcn_update_dpp(
        0, __float_as_int(v), CTRL, 0xf, 0xf, false));
}

// ---------------- RMSNorm row inverse-scale ----------------
__global__ __launch_bounds__(256) void rms_inv_k(const float* __restrict__ x,
                                                 float* __restrict__ inv) {
    int row = blockIdx.x;
    float4 v = ((const float4*)(x + (size_t)row * DMODEL))[threadIdx.x];
    float s = v.x * v.x + v.y * v.y + v.z * v.z + v.w * v.w;
#pragma unroll
    for (int m = 32; m >= 1; m >>= 1) s += __shfl_xor(s, m);
    __shared__ float wsum[4];
    if ((threadIdx.x & 63) == 0) wsum[threadIdx.x >> 6] = s;
    __syncthreads();
    if (threadIdx.x == 0) {
        float tot = wsum[0] + wsum[1] + wsum[2] + wsum[3];
        inv[row] = rsqrtf(tot * (1.f / (float)DMODEL) + 1e-6f);
    }
}

// ---------------- Generic NT GEMM: C = A(MxK,lda) * W(NxK)^T ----------------
template <int EPI, bool NORMA>
__global__ __launch_bounds__(256) void gemm_nt(
    const float* __restrict__ A, int lda,
    const float* __restrict__ W,
    float* __restrict__ C, int ldc,
    int M, int N, int K,
    const float* __restrict__ rowscale,
    const float* __restrict__ kscale,
    const float* __restrict__ bias,
    const float* __restrict__ residual,
    const int* __restrict__ lengths) {
    __shared__ float As[16][68];
    __shared__ float Ws[16][68];
    const int t = threadIdx.x;
    const int row0 = blockIdx.y * 64;
    const int col0 = blockIdx.x * 64;
    const int lm = t >> 2;
    const int lk = (t & 3) << 2;
    const int tx = t & 15, ty = t >> 4;
    const int arow = row0 + lm;
    const int wcol = col0 + lm;
    float rs = NORMA ? rowscale[arow] : 1.f;
    float acc[4][4] = {};
    for (int k0 = 0; k0 < K; k0 += 16) {
        float4 av = *(const float4*)(A + (size_t)arow * lda + k0 + lk);
        if (NORMA) {
            float4 nw = *(const float4*)(kscale + k0 + lk);
            av.x *= rs * nw.x; av.y *= rs * nw.y;
            av.z *= rs * nw.z; av.w *= rs * nw.w;
        }
        As[lk + 0][lm] = av.x; As[lk + 1][lm] = av.y;
        As[lk + 2][lm] = av.z; As[lk + 3][lm] = av.w;
        float4 wv = make_float4(0.f, 0.f, 0.f, 0.f);
        if (wcol < N) wv = *(const float4*)(W + (size_t)wcol * K + k0 + lk);
        Ws[lk + 0][lm] = wv.x; Ws[lk + 1][lm] = wv.y;
        Ws[lk + 2][lm] = wv.z; Ws[lk + 3][lm] = wv.w;
        __syncthreads();
#pragma unroll
        for (int kk = 0; kk < 16; ++kk) {
            float a_[4], b_[4];
#pragma unroll
            for (int i = 0; i < 4; ++i) a_[i] = As[kk][ty * 4 + i];
#pragma unroll
            for (int j = 0; j < 4; ++j) b_[j] = Ws[kk][tx * 4 + j];
#pragma unroll
            for (int i = 0; i < 4; ++i)
#pragma unroll
                for (int j = 0; j < 4; ++j)
                    acc[i][j] = fmaf(a_[i], b_[j], acc[i][j]);
        }
        __syncthreads();
    }
#pragma unroll
    for (int i = 0; i < 4; ++i) {
        int row = row0 + ty * 4 + i;
        float msk = 1.f;
        if (EPI != 0) {
            int b = row >> 11, l = row & (LSEQ - 1);
            msk = (l < lengths[b]) ? 1.f : 0.f;
        }
#pragma unroll
        for (int j = 0; j < 4; ++j) {
            int col = col0 + tx * 4 + j;
            if (col < N) {
                float v = acc[i][j];
                if (EPI == 1) {
                    v += bias[col];
                    v = (v > 20.f) ? v : log1pf(expf(v));
                    v *= msk;
                } else if (EPI == 2) {
                    v = residual[(size_t)row * N + col] + msk * v;
                }
                C[(size_t)row * ldc + col] = v;
            }
        }
    }
}

// ---------------- causal depthwise conv (K=4) + SiLU + mask ----------------
__global__ __launch_bounds__(256) void conv_silu_k(const float* __restrict__ xz,
                                                   const float* __restrict__ cw,
                                                   const int* __restrict__ lengths,
                                                   float* __restrict__ u) {
    int row = blockIdx.x;
    int b = row >> 11, l = row & (LSEQ - 1);
    int len = lengths[b];
    bool act = l < len;
    for (int d = threadIdx.x; d < DINNER; d += 256) {
        float4 w = *(const float4*)(cw + 4 * d);
        float wk[4] = {w.x, w.y, w.z, w.w};
        float acc = 0.f;
        int lp = l - 3;
#pragma unroll
        for (int k = 0; k < 4; ++k, ++lp) {
            if (lp >= 0 && lp < len)
                acc = fmaf(wk[k], xz[((size_t)(b * LSEQ + lp)) * 4096 + d], acc);
        }
        u[(size_t)row * DINNER + d] = act ? siluf(acc) : 0.f;
    }
}

// ---------------- selective scan, LDS time-tiled ----------------
// block = 256 threads = 16 channels x 16 states; grid = NB * (DINNER/16)
__global__ __launch_bounds__(256) void scan_k(const float* __restrict__ xz,  // delta 0..2047, z 2048..4095
                                              float* u_y,                    // u in, y out (in-place)
                                              const float* __restrict__ xdbl,// (8192,96): B at 64, C at 80
                                              const float* __restrict__ A_log,
                                              const float* __restrict__ D_skip,
                                              float* __restrict__ out_h) {
    __shared__ float sD[TT][16], sU[TT][16], sB[TT][16], sC[TT][16], sY[TT][16];
    const int t = threadIdx.x;
    const int b = blockIdx.x >> 7;
    const int d0 = (blockIdx.x & 127) << 4;
    // load/store mapping: one float4 per row-quarter
    const int lr = t >> 2;            // 0..63 (tile row)
    const int lq = (t & 3) << 2;      // 0,4,8,12 (col offset)
    // compute mapping
    const int ch = t >> 4, n = t & 15;
    const int d = d0 + ch;
    const float Av = -__expf(A_log[d * NST + n]);
    const float Dv = D_skip[d];
    float h = 0.f;
    const size_t base = (size_t)b * LSEQ;

    for (int l0 = 0; l0 < LSEQ; l0 += TT) {
        const size_t row = base + l0 + lr;
        float4 dv = *(const float4*)(xz + row * 4096 + d0 + lq);
        float4 uv = *(const float4*)(u_y + row * DINNER + d0 + lq);
        float4 zv = *(const float4*)(xz + row * 4096 + DINNER + d0 + lq);
        float4 bv = *(const float4*)(xdbl + row * 96 + 64 + lq);
        float4 cv = *(const float4*)(xdbl + row * 96 + 80 + lq);
        *(float4*)&sD[lr][lq] = dv;
        *(float4*)&sU[lr][lq] = uv;
        *(float4*)&sB[lr][lq] = bv;
        *(float4*)&sC[lr][lq] = cv;
        __syncthreads();

#pragma unroll 4
        for (int r = 0; r < TT; ++r) {
            float dl = sD[r][ch];
            float ul = sU[r][ch];
            float Bn = sB[r][n];
            float Cn = sC[r][n];
            float dA = __expf(dl * Av);
            h = fmaf(dA, h, dl * ul * Bn);
            float p = h * Cn;
            p += dpp_ror<0x128>(p);   // ror 8
            p += dpp_ror<0x124>(p);   // ror 4
            p += dpp_ror<0x122>(p);   // ror 2
            p += dpp_ror<0x121>(p);   // ror 1
            if (n == 0) sY[r][ch] = fmaf(ul, Dv, p);
        }
        __syncthreads();

        // store phase: gate with silu(z) (z prefetched in registers) and write back
        float4 yv = *(const float4*)&sY[lr][lq];
        yv.x *= siluf(zv.x); yv.y *= siluf(zv.y);
        yv.z *= siluf(zv.z); yv.w *= siluf(zv.w);
        *(float4*)(u_y + row * DINNER + d0 + lq) = yv;
    }
    out_h[((size_t)(b * DINNER + d)) * NST + n] = h;
}

extern "C" void kernel_launch(void* const* d_in, const int* in_sizes, int n_in,
                              void* d_out, int out_size, void* d_ws, size_t ws_size,
                              hipStream_t stream) {
    const float* hs        = (const float*)d_in[0];
    const int*   lengths   = (const int*)d_in[1];
    const float* norm_w    = (const float*)d_in[2];
    const float* in_proj_w = (const float*)d_in[3];
    const float* conv_w    = (const float*)d_in[4];
    const float* x_proj_w  = (const float*)d_in[5];
    const float* dt_proj_w = (const float*)d_in[6];
    const float* dt_proj_b = (const float*)d_in[7];
    const float* A_log     = (const float*)d_in[8];
    const float* D_skip    = (const float*)d_in[9];
    const float* out_proj_w= (const float*)d_in[10];

    float* out = (float*)d_out;
    float* ws  = (float*)d_ws;

    const int M = NB * LSEQ;                 // 8192
    float* inv  = ws;                        // 8192 floats
    float* xz   = inv + 8192;                // 8192 x 4096
    float* u    = xz + (size_t)M * 4096;     // 8192 x 2048 (becomes y in-place)
    float* xdbl = u + (size_t)M * DINNER;    // 8192 x 96

    // 1. RMSNorm row scales
    rms_inv_k<<<M, 256, 0, stream>>>(hs, inv);

    // 2. in_proj: xz = rmsnorm(x) @ in_proj_w^T   (8192 x 4096, K=1024)
    {
        dim3 g(4096 / 64, M / 64);
        gemm_nt<0, true><<<g, 256, 0, stream>>>(hs, DMODEL, in_proj_w, xz, 4096,
                                                M, 4096, DMODEL,
                                                inv, norm_w, nullptr, nullptr, nullptr);
    }

    // 3. causal depthwise conv + silu + mask: u
    conv_silu_k<<<M, 256, 0, stream>>>(xz, conv_w, lengths, u);

    // 4. x_proj: xdbl = u @ x_proj_w^T  (8192 x 96, K=2048)
    {
        dim3 g((96 + 63) / 64, M / 64);
        gemm_nt<0, false><<<g, 256, 0, stream>>>(u, DINNER, x_proj_w, xdbl, 96,
                                                 M, 96, DINNER,
                                                 nullptr, nullptr, nullptr, nullptr, nullptr);
    }

    // 5. dt_proj + softplus + mask: delta -> xz cols 0..2047 (u_raw half is dead)
    {
        dim3 g(DINNER / 64, M / 64);
        gemm_nt<1, false><<<g, 256, 0, stream>>>(xdbl, 96, dt_proj_w, xz, 4096,
                                                 M, DINNER, 64,
                                                 nullptr, nullptr, dt_proj_b, nullptr, lengths);
    }

    // 6. selective scan: y (in-place over u), h_last -> tail of d_out
    {
        float* hlast = out + (size_t)M * DMODEL;
        scan_k<<<NB * (DINNER / 16), 256, 0, stream>>>(xz, u, xdbl, A_log, D_skip, hlast);
    }

    // 7. out_proj + residual + mask -> d_out
    {
        dim3 g(DMODEL / 64, M / 64);
        gemm_nt<2, false><<<g, 256, 0, stream>>>(u, DINNER, out_proj_w, out, DMODEL,
                                                 M, DMODEL, DINNER,
                                                 nullptr, nullptr, nullptr, hs, lengths);
    }
}

// Round 3
// 585.683 us; speedup vs baseline: 5.4810x; 3.1509x over previous
//
#include <hip/hip_runtime.h>
#include <cstdint>
#include <cstddef>

#define LSEQ 2048
#define NB   4
#define DMODEL 1024
#define DINNER 2048
#define NST  16
#define TT   64   // scan time-tile

typedef short bf16x8 __attribute__((ext_vector_type(8)));
typedef float f32x4  __attribute__((ext_vector_type(4)));

__device__ __forceinline__ float siluf(float x) { return x / (1.f + __expf(-x)); }

__device__ __forceinline__ unsigned short f2bf(float f) {
    unsigned u = __float_as_uint(f);
    u += 0x7FFF + ((u >> 16) & 1);     // round-to-nearest-even
    return (unsigned short)(u >> 16);
}
__device__ __forceinline__ float bf2f(unsigned short h) {
    return __uint_as_float(((unsigned)h) << 16);
}
__device__ __forceinline__ void gload_lds16(const void* g, void* l) {
    __builtin_amdgcn_global_load_lds(
        (const __attribute__((address_space(1))) unsigned int*)g,
        (__attribute__((address_space(3))) unsigned int*)l, 16, 0, 0);
}

template <int CTRL>
__device__ __forceinline__ float dpp_ror(float v) {
    return __int_as_float(__builtin_amdgcn_update_dpp(
        0, __float_as_int(v), CTRL, 0xf, 0xf, false));
}

// ---------------- RMSNorm row inverse-scale ----------------
__global__ __launch_bounds__(256) void rms_inv_k(const float* __restrict__ x,
                                                 float* __restrict__ inv) {
    int row = blockIdx.x;
    float4 v = ((const float4*)(x + (size_t)row * DMODEL))[threadIdx.x];
    float s = v.x * v.x + v.y * v.y + v.z * v.z + v.w * v.w;
#pragma unroll
    for (int m = 32; m >= 1; m >>= 1) s += __shfl_xor(s, m);
    __shared__ float wsum[4];
    if ((threadIdx.x & 63) == 0) wsum[threadIdx.x >> 6] = s;
    __syncthreads();
    if (threadIdx.x == 0) {
        float tot = wsum[0] + wsum[1] + wsum[2] + wsum[3];
        inv[row] = rsqrtf(tot * (1.f / (float)DMODEL) + 1e-6f);
    }
}

// ---------------- normed activation -> bf16 ----------------
__global__ __launch_bounds__(256) void normcvt_k(const float* __restrict__ x,
                                                 const float* __restrict__ inv,
                                                 const float* __restrict__ nw,
                                                 unsigned short* __restrict__ o) {
    int row = blockIdx.x, t = threadIdx.x;
    float s = inv[row];
    float4 v = ((const float4*)(x + (size_t)row * DMODEL))[t];
    float4 w = ((const float4*)nw)[t];
    ushort4 ov;
    ov.x = f2bf(v.x * s * w.x); ov.y = f2bf(v.y * s * w.y);
    ov.z = f2bf(v.z * s * w.z); ov.w = f2bf(v.w * s * w.w);
    ((ushort4*)(o + (size_t)row * DMODEL))[t] = ov;
}

// ---------------- flat f32 -> bf16 ----------------
__global__ __launch_bounds__(256) void cvt_bf_k(const float* __restrict__ src,
                                                unsigned short* __restrict__ dst, int n4) {
    int i = blockIdx.x * 256 + threadIdx.x;
    if (i < n4) {
        float4 v = ((const float4*)src)[i];
        ushort4 o;
        o.x = f2bf(v.x); o.y = f2bf(v.y); o.z = f2bf(v.z); o.w = f2bf(v.w);
        ((ushort4*)dst)[i] = o;
    }
}

// ---------------- bf16 MFMA NT GEMM: C(MxN,f32) = A(MxK) * W(NxK)^T ----------------
// 128x128 tile, BK=64, 4 waves (2x2), 4x4 fragments of 16x16x32.
// EPI 0: plain store.  EPI 2: residual + mask.
template <int EPI>
__global__ __launch_bounds__(256) void gemm_bf16(
    const unsigned short* __restrict__ A, int lda,
    const unsigned short* __restrict__ W, int ldw,
    float* __restrict__ C, int ldc,
    int M, int N, int K, int nbx,
    const float* __restrict__ residual,
    const int* __restrict__ lengths) {
    __shared__ __align__(16) unsigned short As[128 * 64];
    __shared__ __align__(16) unsigned short Bs[128 * 64];
    const int nwg = gridDim.x;
    const int bid = blockIdx.x;
    const int cpx = nwg >> 3;                       // nwg % 8 == 0 for all our launches
    const int swz = (bid & 7) * cpx + (bid >> 3);
    const int bx = swz % nbx, by = swz / nbx;
    const int row0 = by * 128, col0 = bx * 128;
    const int t = threadIdx.x;
    const int lane = t & 63;
    const int w = t >> 6;
    const int wr = w >> 1, wc = w & 1;

    f32x4 acc[4][4];
#pragma unroll
    for (int m = 0; m < 4; ++m)
#pragma unroll
        for (int n = 0; n < 4; ++n) acc[m][n] = f32x4{0.f, 0.f, 0.f, 0.f};

    const int rA = lane & 15;
    const int kH = (lane >> 4) << 3;

    for (int k0 = 0; k0 < K; k0 += 64) {
#pragma unroll
        for (int it = 0; it < 4; ++it) {
            int c = it * 256 + t;
            int r = c >> 3, cc = (c & 7) << 3;
            gload_lds16(A + (size_t)(row0 + r) * lda + k0 + cc, &As[c << 3]);
            int wrow = col0 + r; if (wrow >= N) wrow = N - 1;   // clamp (x_proj N=96)
            gload_lds16(W + (size_t)wrow * ldw + k0 + cc, &Bs[c << 3]);
        }
        __syncthreads();
#pragma unroll
        for (int ks = 0; ks < 2; ++ks) {
            const int kk = ks * 32 + kH;
            bf16x8 af[4], bfr[4];
#pragma unroll
            for (int m = 0; m < 4; ++m)
                af[m] = *(const bf16x8*)&As[(wr * 64 + m * 16 + rA) * 64 + kk];
#pragma unroll
            for (int n = 0; n < 4; ++n)
                bfr[n] = *(const bf16x8*)&Bs[(wc * 64 + n * 16 + rA) * 64 + kk];
#pragma unroll
            for (int m = 0; m < 4; ++m)
#pragma unroll
                for (int n = 0; n < 4; ++n)
                    acc[m][n] = __builtin_amdgcn_mfma_f32_16x16x32_bf16(
                        af[m], bfr[n], acc[m][n], 0, 0, 0);
        }
        __syncthreads();
    }
    // epilogue: D[row][col], col = lane&15, row = (lane>>4)*4 + j
    const int cl = lane & 15, rg = lane >> 4;
#pragma unroll
    for (int m = 0; m < 4; ++m) {
#pragma unroll
        for (int j = 0; j < 4; ++j) {
            const int row = row0 + wr * 64 + m * 16 + rg * 4 + j;
            float msk = 1.f;
            if (EPI == 2) {
                int bb = row >> 11, ll = row & (LSEQ - 1);
                msk = (ll < lengths[bb]) ? 1.f : 0.f;
            }
#pragma unroll
            for (int n = 0; n < 4; ++n) {
                const int col = col0 + wc * 64 + n * 16 + cl;
                if (col < N) {
                    float v = acc[m][n][j];
                    if (EPI == 2) v = residual[(size_t)row * N + col] + msk * v;
                    C[(size_t)row * ldc + col] = v;
                }
            }
        }
    }
}

// ---------------- fp32 NT GEMM (dt_proj only, K=64) ----------------
template <int EPI, bool NORMA>
__global__ __launch_bounds__(256) void gemm_nt(
    const float* __restrict__ A, int lda,
    const float* __restrict__ W,
    float* __restrict__ C, int ldc,
    int M, int N, int K,
    const float* __restrict__ rowscale,
    const float* __restrict__ kscale,
    const float* __restrict__ bias,
    const float* __restrict__ residual,
    const int* __restrict__ lengths) {
    __shared__ float As[16][68];
    __shared__ float Ws[16][68];
    const int t = threadIdx.x;
    const int row0 = blockIdx.y * 64;
    const int col0 = blockIdx.x * 64;
    const int lm = t >> 2;
    const int lk = (t & 3) << 2;
    const int tx = t & 15, ty = t >> 4;
    const int arow = row0 + lm;
    const int wcol = col0 + lm;
    float acc[4][4] = {};
    for (int k0 = 0; k0 < K; k0 += 16) {
        float4 av = *(const float4*)(A + (size_t)arow * lda + k0 + lk);
        As[lk + 0][lm] = av.x; As[lk + 1][lm] = av.y;
        As[lk + 2][lm] = av.z; As[lk + 3][lm] = av.w;
        float4 wv = make_float4(0.f, 0.f, 0.f, 0.f);
        if (wcol < N) wv = *(const float4*)(W + (size_t)wcol * K + k0 + lk);
        Ws[lk + 0][lm] = wv.x; Ws[lk + 1][lm] = wv.y;
        Ws[lk + 2][lm] = wv.z; Ws[lk + 3][lm] = wv.w;
        __syncthreads();
#pragma unroll
        for (int kk = 0; kk < 16; ++kk) {
            float a_[4], b_[4];
#pragma unroll
            for (int i = 0; i < 4; ++i) a_[i] = As[kk][ty * 4 + i];
#pragma unroll
            for (int j = 0; j < 4; ++j) b_[j] = Ws[kk][tx * 4 + j];
#pragma unroll
            for (int i = 0; i < 4; ++i)
#pragma unroll
                for (int j = 0; j < 4; ++j)
                    acc[i][j] = fmaf(a_[i], b_[j], acc[i][j]);
        }
        __syncthreads();
    }
#pragma unroll
    for (int i = 0; i < 4; ++i) {
        int row = row0 + ty * 4 + i;
        float msk = 1.f;
        if (EPI != 0) {
            int b = row >> 11, l = row & (LSEQ - 1);
            msk = (l < lengths[b]) ? 1.f : 0.f;
        }
#pragma unroll
        for (int j = 0; j < 4; ++j) {
            int col = col0 + tx * 4 + j;
            if (col < N) {
                float v = acc[i][j];
                if (EPI == 1) {
                    v += bias[col];
                    v = (v > 20.f) ? v : log1pf(expf(v));
                    v *= msk;
                } else if (EPI == 2) {
                    v = residual[(size_t)row * N + col] + msk * v;
                }
                C[(size_t)row * ldc + col] = v;
            }
        }
    }
}

// ---------------- causal depthwise conv (K=4) + SiLU + mask -> bf16 ----------------
__global__ __launch_bounds__(256) void conv_silu_k(const float* __restrict__ xz,
                                                   const float* __restrict__ cw,
                                                   const int* __restrict__ lengths,
                                                   unsigned short* __restrict__ u) {
    int row = blockIdx.x;
    int b = row >> 11, l = row & (LSEQ - 1);
    int len = lengths[b];
    bool act = l < len;
    for (int d = threadIdx.x; d < DINNER; d += 256) {
        float4 w = *(const float4*)(cw + 4 * d);
        float wk[4] = {w.x, w.y, w.z, w.w};
        float acc = 0.f;
        int lp = l - 3;
#pragma unroll
        for (int k = 0; k < 4; ++k, ++lp) {
            if (lp >= 0 && lp < len)
                acc = fmaf(wk[k], xz[((size_t)(b * LSEQ + lp)) * 4096 + d], acc);
        }
        u[(size_t)row * DINNER + d] = f2bf(act ? siluf(acc) : 0.f);
    }
}

// ---------------- selective scan, LDS time-tiled ----------------
// u (bf16) in, y (bf16) out in-place; h_last -> out_h
__global__ __launch_bounds__(256) void scan_k(const float* __restrict__ xz,   // delta 0.., z 2048..
                                              unsigned short* uy,             // bf16 u in / y out
                                              const float* __restrict__ xdbl, // (8192,96): B@64, C@80
                                              const float* __restrict__ A_log,
                                              const float* __restrict__ D_skip,
                                              float* __restrict__ out_h) {
    __shared__ float sD[TT][16], sU[TT][16], sB[TT][16], sC[TT][16], sY[TT][16];
    const int t = threadIdx.x;
    const int b = blockIdx.x >> 7;
    const int d0 = (blockIdx.x & 127) << 4;
    const int lr = t >> 2;
    const int lq = (t & 3) << 2;
    const int ch = t >> 4, n = t & 15;
    const int d = d0 + ch;
    const float Av = -__expf(A_log[d * NST + n]);
    const float Dv = D_skip[d];
    float h = 0.f;
    const size_t base = (size_t)b * LSEQ;

    for (int l0 = 0; l0 < LSEQ; l0 += TT) {
        const size_t row = base + l0 + lr;
        float4 dv = *(const float4*)(xz + row * 4096 + d0 + lq);
        ushort4 uv = *(const ushort4*)(uy + row * DINNER + d0 + lq);
        float4 zv = *(const float4*)(xz + row * 4096 + DINNER + d0 + lq);
        float4 bv = *(const float4*)(xdbl + row * 96 + 64 + lq);
        float4 cv = *(const float4*)(xdbl + row * 96 + 80 + lq);
        *(float4*)&sD[lr][lq] = dv;
        sU[lr][lq + 0] = bf2f(uv.x); sU[lr][lq + 1] = bf2f(uv.y);
        sU[lr][lq + 2] = bf2f(uv.z); sU[lr][lq + 3] = bf2f(uv.w);
        *(float4*)&sB[lr][lq] = bv;
        *(float4*)&sC[lr][lq] = cv;
        __syncthreads();

#pragma unroll 4
        for (int r = 0; r < TT; ++r) {
            float dl = sD[r][ch];
            float ul = sU[r][ch];
            float Bn = sB[r][n];
            float Cn = sC[r][n];
            float dA = __expf(dl * Av);
            h = fmaf(dA, h, dl * ul * Bn);
            float p = h * Cn;
            p += dpp_ror<0x128>(p);
            p += dpp_ror<0x124>(p);
            p += dpp_ror<0x122>(p);
            p += dpp_ror<0x121>(p);
            if (n == 0) sY[r][ch] = fmaf(ul, Dv, p);
        }
        __syncthreads();

        float4 yv = *(const float4*)&sY[lr][lq];
        ushort4 ov;
        ov.x = f2bf(yv.x * siluf(zv.x)); ov.y = f2bf(yv.y * siluf(zv.y));
        ov.z = f2bf(yv.z * siluf(zv.z)); ov.w = f2bf(yv.w * siluf(zv.w));
        *(ushort4*)(uy + row * DINNER + d0 + lq) = ov;
    }
    out_h[((size_t)(b * DINNER + d)) * NST + n] = h;
}

extern "C" void kernel_launch(void* const* d_in, const int* in_sizes, int n_in,
                              void* d_out, int out_size, void* d_ws, size_t ws_size,
                              hipStream_t stream) {
    const float* hs        = (const float*)d_in[0];
    const int*   lengths   = (const int*)d_in[1];
    const float* norm_w    = (const float*)d_in[2];
    const float* in_proj_w = (const float*)d_in[3];
    const float* conv_w    = (const float*)d_in[4];
    const float* x_proj_w  = (const float*)d_in[5];
    const float* dt_proj_w = (const float*)d_in[6];
    const float* dt_proj_b = (const float*)d_in[7];
    const float* A_log     = (const float*)d_in[8];
    const float* D_skip    = (const float*)d_in[9];
    const float* out_proj_w= (const float*)d_in[10];

    float* out = (float*)d_out;
    float* ws  = (float*)d_ws;

    const int M = NB * LSEQ;                          // 8192
    float* inv = ws;                                  // 8192 f
    float* xz  = inv + 8192;                          // 8192x4096 f (128MB)
    unsigned short* u_bf = (unsigned short*)(xz + (size_t)M * 4096);  // 8192x2048 bf16 (32MB)
    float* xdbl = (float*)(u_bf + (size_t)M * DINNER);                // 8192x96 f (3MB)
    unsigned short* w_in  = (unsigned short*)(xdbl + (size_t)M * 96); // 4096x1024
    unsigned short* w_out = w_in + (size_t)4096 * 1024;               // 1024x2048
    unsigned short* w_x   = w_out + (size_t)1024 * 2048;              // 96x2048
    unsigned short* xn_bf = u_bf;  // alias: dead once conv overwrites it

    // 1. RMSNorm scales + bf16 conversions
    rms_inv_k<<<M, 256, 0, stream>>>(hs, inv);
    normcvt_k<<<M, 256, 0, stream>>>(hs, inv, norm_w, xn_bf);
    cvt_bf_k<<<4096, 256, 0, stream>>>(in_proj_w, w_in, 1048576);
    cvt_bf_k<<<2048, 256, 0, stream>>>(out_proj_w, w_out, 524288);
    cvt_bf_k<<<192, 256, 0, stream>>>(x_proj_w, w_x, 49152);

    // 2. in_proj (bf16 MFMA): xz = xn @ in_proj_w^T   (8192x4096, K=1024)
    gemm_bf16<0><<<(4096 / 128) * (M / 128), 256, 0, stream>>>(
        xn_bf, DMODEL, w_in, DMODEL, xz, 4096, M, 4096, DMODEL, 4096 / 128,
        nullptr, nullptr);

    // 3. causal depthwise conv + silu + mask -> u (bf16)
    conv_silu_k<<<M, 256, 0, stream>>>(xz, conv_w, lengths, u_bf);

    // 4. x_proj (bf16 MFMA): xdbl = u @ x_proj_w^T  (8192x96, K=2048)
    gemm_bf16<0><<<1 * (M / 128), 256, 0, stream>>>(
        u_bf, DINNER, w_x, DINNER, xdbl, 96, M, 96, DINNER, 1,
        nullptr, nullptr);

    // 5. dt_proj + softplus + mask (fp32): delta -> xz cols 0..2047
    {
        dim3 g(DINNER / 64, M / 64);
        gemm_nt<1, false><<<g, 256, 0, stream>>>(xdbl, 96, dt_proj_w, xz, 4096,
                                                 M, DINNER, 64,
                                                 nullptr, nullptr, dt_proj_b, nullptr, lengths);
    }

    // 6. selective scan: y (bf16, in-place over u), h_last -> tail of d_out
    {
        float* hlast = out + (size_t)M * DMODEL;
        scan_k<<<NB * (DINNER / 16), 256, 0, stream>>>(xz, u_bf, xdbl, A_log, D_skip, hlast);
    }

    // 7. out_proj (bf16 MFMA) + residual + mask -> d_out
    gemm_bf16<2><<<(DMODEL / 128) * (M / 128), 256, 0, stream>>>(
        u_bf, DINNER, w_out, DINNER, out, DMODEL, M, DMODEL, DINNER, DMODEL / 128,
        hs, lengths);
}

// Round 4
// 531.725 us; speedup vs baseline: 6.0372x; 1.1015x over previous
//
#include <hip/hip_runtime.h>
#include <cstdint>
#include <cstddef>

#define LSEQ 2048
#define NB   4
#define DMODEL 1024
#define DINNER 2048
#define NST  16
#define TT   64   // scan time-tile

typedef short bf16x8 __attribute__((ext_vector_type(8)));
typedef float f32x4  __attribute__((ext_vector_type(4)));

__device__ __forceinline__ float siluf(float x) { return x / (1.f + __expf(-x)); }

__device__ __forceinline__ unsigned short f2bf(float f) {
    unsigned u = __float_as_uint(f);
    u += 0x7FFF + ((u >> 16) & 1);     // round-to-nearest-even
    return (unsigned short)(u >> 16);
}
__device__ __forceinline__ float bf2f(unsigned short h) {
    return __uint_as_float(((unsigned)h) << 16);
}
__device__ __forceinline__ void gload_lds16(const void* g, void* l) {
    __builtin_amdgcn_global_load_lds(
        (const __attribute__((address_space(1))) unsigned int*)g,
        (__attribute__((address_space(3))) unsigned int*)l, 16, 0, 0);
}

template <int CTRL>
__device__ __forceinline__ float dpp_ror(float v) {
    return __int_as_float(__builtin_amdgcn_update_dpp(
        0, __float_as_int(v), CTRL, 0xf, 0xf, false));
}

// ---------------- fused RMSNorm + bf16 convert ----------------
__global__ __launch_bounds__(256) void rmsnorm_cvt_k(const float* __restrict__ x,
                                                     const float* __restrict__ nw,
                                                     unsigned short* __restrict__ o) {
    int row = blockIdx.x, t = threadIdx.x;
    float4 v = ((const float4*)(x + (size_t)row * DMODEL))[t];
    float s = v.x * v.x + v.y * v.y + v.z * v.z + v.w * v.w;
#pragma unroll
    for (int m = 32; m >= 1; m >>= 1) s += __shfl_xor(s, m);
    __shared__ float wsum[4];
    __shared__ float sinv;
    if ((t & 63) == 0) wsum[t >> 6] = s;
    __syncthreads();
    if (t == 0) {
        float tot = wsum[0] + wsum[1] + wsum[2] + wsum[3];
        sinv = rsqrtf(tot * (1.f / (float)DMODEL) + 1e-6f);
    }
    __syncthreads();
    float iv = sinv;
    float4 w = ((const float4*)nw)[t];
    ushort4 ov;
    ov.x = f2bf(v.x * iv * w.x); ov.y = f2bf(v.y * iv * w.y);
    ov.z = f2bf(v.z * iv * w.z); ov.w = f2bf(v.w * iv * w.w);
    ((ushort4*)(o + (size_t)row * DMODEL))[t] = ov;
}

// ---------------- flat f32 -> bf16 ----------------
__global__ __launch_bounds__(256) void cvt_bf_k(const float* __restrict__ src,
                                                unsigned short* __restrict__ dst, int n4) {
    int i = blockIdx.x * 256 + threadIdx.x;
    if (i < n4) {
        float4 v = ((const float4*)src)[i];
        ushort4 o;
        o.x = f2bf(v.x); o.y = f2bf(v.y); o.z = f2bf(v.z); o.w = f2bf(v.w);
        ((ushort4*)dst)[i] = o;
    }
}

// ---------------- extract dt_r (cols 0..63 of xdbl) -> bf16 ----------------
__global__ __launch_bounds__(256) void dtr_cvt_k(const float* __restrict__ xdbl,
                                                 unsigned short* __restrict__ dtr) {
    int idx = blockIdx.x * 256 + threadIdx.x;    // 131072 total
    int row = idx >> 4, c4 = (idx & 15) << 2;
    float4 v = *(const float4*)(xdbl + (size_t)row * 96 + c4);
    ushort4 o;
    o.x = f2bf(v.x); o.y = f2bf(v.y); o.z = f2bf(v.z); o.w = f2bf(v.w);
    *(ushort4*)(dtr + (size_t)row * 64 + c4) = o;
}

// ---------------- bf16 MFMA NT GEMM: C(MxN,f32) = A(MxK) * W(NxK)^T ----------------
// 128x128 tile, BK=64, 4 waves (2x2), 4x4 fragments of 16x16x32.
// EPI 0: plain store.  EPI 1: softplus(acc+bias)*mask.  EPI 2: residual + mask*acc.
template <int EPI>
__global__ __launch_bounds__(256) void gemm_bf16(
    const unsigned short* __restrict__ A, int lda,
    const unsigned short* __restrict__ W, int ldw,
    float* __restrict__ C, int ldc,
    int M, int N, int K, int nbx,
    const float* __restrict__ bias,
    const float* __restrict__ residual,
    const int* __restrict__ lengths) {
    __shared__ __align__(16) unsigned short As[128 * 64];
    __shared__ __align__(16) unsigned short Bs[128 * 64];
    const int nwg = gridDim.x;
    const int bid = blockIdx.x;
    const int cpx = nwg >> 3;                       // nwg % 8 == 0 for all launches
    const int swz = (bid & 7) * cpx + (bid >> 3);
    const int bx = swz % nbx, by = swz / nbx;
    const int row0 = by * 128, col0 = bx * 128;
    const int t = threadIdx.x;
    const int lane = t & 63;
    const int w = t >> 6;
    const int wr = w >> 1, wc = w & 1;

    f32x4 acc[4][4];
#pragma unroll
    for (int m = 0; m < 4; ++m)
#pragma unroll
        for (int n = 0; n < 4; ++n) acc[m][n] = f32x4{0.f, 0.f, 0.f, 0.f};

    const int rA = lane & 15;
    const int kH = (lane >> 4) << 3;

    for (int k0 = 0; k0 < K; k0 += 64) {
#pragma unroll
        for (int it = 0; it < 4; ++it) {
            int c = it * 256 + t;
            int r = c >> 3, cc = (c & 7) << 3;
            gload_lds16(A + (size_t)(row0 + r) * lda + k0 + cc, &As[c << 3]);
            int wrow = col0 + r; if (wrow >= N) wrow = N - 1;   // clamp (x_proj N=96)
            gload_lds16(W + (size_t)wrow * ldw + k0 + cc, &Bs[c << 3]);
        }
        __syncthreads();
#pragma unroll
        for (int ks = 0; ks < 2; ++ks) {
            const int kk = ks * 32 + kH;
            bf16x8 af[4], bfr[4];
#pragma unroll
            for (int m = 0; m < 4; ++m)
                af[m] = *(const bf16x8*)&As[(wr * 64 + m * 16 + rA) * 64 + kk];
#pragma unroll
            for (int n = 0; n < 4; ++n)
                bfr[n] = *(const bf16x8*)&Bs[(wc * 64 + n * 16 + rA) * 64 + kk];
#pragma unroll
            for (int m = 0; m < 4; ++m)
#pragma unroll
                for (int n = 0; n < 4; ++n)
                    acc[m][n] = __builtin_amdgcn_mfma_f32_16x16x32_bf16(
                        af[m], bfr[n], acc[m][n], 0, 0, 0);
        }
        __syncthreads();
    }
    const int cl = lane & 15, rg = lane >> 4;
#pragma unroll
    for (int m = 0; m < 4; ++m) {
#pragma unroll
        for (int j = 0; j < 4; ++j) {
            const int row = row0 + wr * 64 + m * 16 + rg * 4 + j;
            float msk = 1.f;
            if (EPI != 0) {
                int bb = row >> 11, ll = row & (LSEQ - 1);
                msk = (ll < lengths[bb]) ? 1.f : 0.f;
            }
#pragma unroll
            for (int n = 0; n < 4; ++n) {
                const int col = col0 + wc * 64 + n * 16 + cl;
                if (col < N) {
                    float v = acc[m][n][j];
                    if (EPI == 1) {
                        v += bias[col];
                        v = (v > 20.f) ? v : log1pf(__expf(v));
                        v *= msk;
                    } else if (EPI == 2) {
                        v = residual[(size_t)row * N + col] + msk * v;
                    }
                    C[(size_t)row * ldc + col] = v;
                }
            }
        }
    }
}

// ---------------- causal depthwise conv (K=4) + SiLU + mask -> bf16 ----------------
// sliding window: each thread produces 4 channels x 8 timesteps
__global__ __launch_bounds__(256) void conv_silu_k(const float* __restrict__ xz,
                                                   const float* __restrict__ cw,
                                                   const int* __restrict__ lengths,
                                                   unsigned short* __restrict__ u) {
    const int g = blockIdx.x;              // NB * 512
    const int b = g >> 9;
    const int rem = g & 511;
    const int l0 = (rem >> 1) << 3;
    const int d4 = (rem & 1) * 1024 + threadIdx.x * 4;
    const int len = lengths[b];
    float4 wq[4];
#pragma unroll
    for (int c = 0; c < 4; ++c) wq[c] = *(const float4*)(cw + 4 * (d4 + c));
    const size_t rb = (size_t)b * LSEQ;
    const float4 zero4 = {0.f, 0.f, 0.f, 0.f};
    float4 xm3 = (l0 - 3 >= 0 && l0 - 3 < len) ? *(const float4*)(xz + (rb + l0 - 3) * 4096 + d4) : zero4;
    float4 xm2 = (l0 - 2 >= 0 && l0 - 2 < len) ? *(const float4*)(xz + (rb + l0 - 2) * 4096 + d4) : zero4;
    float4 xm1 = (l0 - 1 >= 0 && l0 - 1 < len) ? *(const float4*)(xz + (rb + l0 - 1) * 4096 + d4) : zero4;
#pragma unroll
    for (int i = 0; i < 8; ++i) {
        const int l = l0 + i;
        const bool act = l < len;
        float4 x0 = act ? *(const float4*)(xz + (rb + l) * 4096 + d4) : zero4;
        float a0 = wq[0].x * xm3.x + wq[0].y * xm2.x + wq[0].z * xm1.x + wq[0].w * x0.x;
        float a1 = wq[1].x * xm3.y + wq[1].y * xm2.y + wq[1].z * xm1.y + wq[1].w * x0.y;
        float a2 = wq[2].x * xm3.z + wq[2].y * xm2.z + wq[2].z * xm1.z + wq[2].w * x0.z;
        float a3 = wq[3].x * xm3.w + wq[3].y * xm2.w + wq[3].z * xm1.w + wq[3].w * x0.w;
        ushort4 ov;
        ov.x = f2bf(act ? siluf(a0) : 0.f);
        ov.y = f2bf(act ? siluf(a1) : 0.f);
        ov.z = f2bf(act ? siluf(a2) : 0.f);
        ov.w = f2bf(act ? siluf(a3) : 0.f);
        *(ushort4*)(u + (rb + l) * DINNER + d4) = ov;
        xm3 = xm2; xm2 = xm1; xm1 = x0;
    }
}

// ---------------- selective scan: diet inner loop + double-buffered tiles ----------------
__global__ __launch_bounds__(256) void scan_k(const float* __restrict__ xz,   // delta 0.., z 2048..
                                              unsigned short* uy,             // bf16 u in / y out
                                              const float* __restrict__ xdbl, // (8192,96): B@64, C@80
                                              const float* __restrict__ A_log,
                                              const float* __restrict__ D_skip,
                                              float* __restrict__ out_h) {
    __shared__ float2 sDU[2][TT][16];   // {delta, delta*u}
    __shared__ float2 sBC[2][TT][16];   // {B, C}
    __shared__ float  sY[TT][16];
    const int t = threadIdx.x;
    const int b = blockIdx.x >> 7;
    const int d0 = (blockIdx.x & 127) << 4;
    const int lr = t >> 2;
    const int lq = (t & 3) << 2;
    const int ch = t >> 4, n = t & 15;
    const int d = d0 + ch;
    const float Av2 = -__expf(A_log[d * NST + n]) * 1.44269504f;  // log2e folded
    const float4 Dv4 = *(const float4*)(D_skip + d0 + lq);
    float h = 0.f;
    const size_t base = (size_t)b * LSEQ;

    // prologue: tile 0 loads
    size_t row = base + lr;
    float4 dv = *(const float4*)(xz + row * 4096 + d0 + lq);
    ushort4 uv = *(const ushort4*)(uy + row * DINNER + d0 + lq);
    float4 zv = *(const float4*)(xz + row * 4096 + DINNER + d0 + lq);
    float4 bv = *(const float4*)(xdbl + row * 96 + 64 + lq);
    float4 cv = *(const float4*)(xdbl + row * 96 + 80 + lq);

    for (int tt = 0; tt < LSEQ / TT; ++tt) {
        const int cur = tt & 1;
        const float uf0 = bf2f(uv.x), uf1 = bf2f(uv.y), uf2 = bf2f(uv.z), uf3 = bf2f(uv.w);
        float4 w0 = {dv.x, dv.x * uf0, dv.y, dv.y * uf1};
        float4 w1 = {dv.z, dv.z * uf2, dv.w, dv.w * uf3};
        *(float4*)&sDU[cur][lr][lq]     = w0;
        *(float4*)&sDU[cur][lr][lq + 2] = w1;
        float4 e0 = {bv.x, cv.x, bv.y, cv.y};
        float4 e1 = {bv.z, cv.z, bv.w, cv.w};
        *(float4*)&sBC[cur][lr][lq]     = e0;
        *(float4*)&sBC[cur][lr][lq + 2] = e1;
        __syncthreads();

        // prefetch next tile into registers (overlaps with compute below)
        float4 dv2 = {}, zv2 = {}, bv2 = {}, cv2 = {};
        ushort4 uv2 = {};
        if (tt < LSEQ / TT - 1) {
            const size_t row2 = base + (size_t)(tt + 1) * TT + lr;
            dv2 = *(const float4*)(xz + row2 * 4096 + d0 + lq);
            uv2 = *(const ushort4*)(uy + row2 * DINNER + d0 + lq);
            zv2 = *(const float4*)(xz + row2 * 4096 + DINNER + d0 + lq);
            bv2 = *(const float4*)(xdbl + row2 * 96 + 64 + lq);
            cv2 = *(const float4*)(xdbl + row2 * 96 + 80 + lq);
        }

#pragma unroll 16
        for (int r = 0; r < TT; ++r) {
            float2 ddu = sDU[cur][r][ch];
            float2 bc  = sBC[cur][r][n];
            float dA = __builtin_amdgcn_exp2f(ddu.x * Av2);
            h = fmaf(dA, h, ddu.y * bc.x);
            float p = h * bc.y;
            p += dpp_ror<0x128>(p);
            p += dpp_ror<0x124>(p);
            p += dpp_ror<0x122>(p);
            p += dpp_ror<0x121>(p);
            if (n == 0) sY[r][ch] = p;
        }
        __syncthreads();

        float4 yv = *(const float4*)&sY[lr][lq];
        ushort4 ov;
        ov.x = f2bf((yv.x + uf0 * Dv4.x) * siluf(zv.x));
        ov.y = f2bf((yv.y + uf1 * Dv4.y) * siluf(zv.y));
        ov.z = f2bf((yv.z + uf2 * Dv4.z) * siluf(zv.z));
        ov.w = f2bf((yv.w + uf3 * Dv4.w) * siluf(zv.w));
        *(ushort4*)(uy + row * DINNER + d0 + lq) = ov;
        row = base + (size_t)(tt + 1) * TT + lr;
        dv = dv2; uv = uv2; zv = zv2; bv = bv2; cv = cv2;
    }
    out_h[((size_t)(b * DINNER + d)) * NST + n] = h;
}

extern "C" void kernel_launch(void* const* d_in, const int* in_sizes, int n_in,
                              void* d_out, int out_size, void* d_ws, size_t ws_size,
                              hipStream_t stream) {
    const float* hs        = (const float*)d_in[0];
    const int*   lengths   = (const int*)d_in[1];
    const float* norm_w    = (const float*)d_in[2];
    const float* in_proj_w = (const float*)d_in[3];
    const float* conv_w    = (const float*)d_in[4];
    const float* x_proj_w  = (const float*)d_in[5];
    const float* dt_proj_w = (const float*)d_in[6];
    const float* dt_proj_b = (const float*)d_in[7];
    const float* A_log     = (const float*)d_in[8];
    const float* D_skip    = (const float*)d_in[9];
    const float* out_proj_w= (const float*)d_in[10];

    float* out = (float*)d_out;
    float* ws  = (float*)d_ws;

    const int M = NB * LSEQ;                                            // 8192
    float* xz = ws;                                                     // 8192x4096 f32
    unsigned short* u_bf = (unsigned short*)(xz + (size_t)M * 4096);    // 8192x2048 bf16
    float* xdbl = (float*)(u_bf + (size_t)M * DINNER);                  // 8192x96 f32
    unsigned short* w_in  = (unsigned short*)(xdbl + (size_t)M * 96);   // 4096x1024
    unsigned short* w_out = w_in + (size_t)4096 * 1024;                 // 1024x2048
    unsigned short* w_x   = w_out + (size_t)1024 * 2048;                // 96x2048
    unsigned short* w_dt  = w_x + (size_t)96 * 2048;                    // 2048x64
    unsigned short* dtr   = w_dt + (size_t)2048 * 64;                   // 8192x64
    unsigned short* xn_bf = u_bf;  // alias: dead once conv overwrites it

    // 1. fused RMSNorm->bf16 + weight conversions
    rmsnorm_cvt_k<<<M, 256, 0, stream>>>(hs, norm_w, xn_bf);
    cvt_bf_k<<<4096, 256, 0, stream>>>(in_proj_w, w_in, 1048576);
    cvt_bf_k<<<2048, 256, 0, stream>>>(out_proj_w, w_out, 524288);
    cvt_bf_k<<<192, 256, 0, stream>>>(x_proj_w, w_x, 49152);
    cvt_bf_k<<<128, 256, 0, stream>>>(dt_proj_w, w_dt, 32768);

    // 2. in_proj (bf16 MFMA): xz = xn @ in_proj_w^T   (8192x4096, K=1024)
    gemm_bf16<0><<<(4096 / 128) * (M / 128), 256, 0, stream>>>(
        xn_bf, DMODEL, w_in, DMODEL, xz, 4096, M, 4096, DMODEL, 4096 / 128,
        nullptr, nullptr, nullptr);

    // 3. causal depthwise conv + silu + mask -> u (bf16)
    conv_silu_k<<<NB * 512, 256, 0, stream>>>(xz, conv_w, lengths, u_bf);

    // 4. x_proj (bf16 MFMA): xdbl = u @ x_proj_w^T  (8192x96, K=2048)
    gemm_bf16<0><<<1 * (M / 128), 256, 0, stream>>>(
        u_bf, DINNER, w_x, DINNER, xdbl, 96, M, 96, DINNER, 1,
        nullptr, nullptr, nullptr);

    // 5. dt_r -> bf16, then dt_proj (bf16 MFMA) + softplus + mask: delta -> xz cols 0..2047
    dtr_cvt_k<<<512, 256, 0, stream>>>(xdbl, dtr);
    gemm_bf16<1><<<(DINNER / 128) * (M / 128), 256, 0, stream>>>(
        dtr, 64, w_dt, 64, xz, 4096, M, DINNER, 64, DINNER / 128,
        dt_proj_b, nullptr, lengths);

    // 6. selective scan: y (bf16, in-place over u), h_last -> tail of d_out
    {
        float* hlast = out + (size_t)M * DMODEL;
        scan_k<<<NB * (DINNER / 16), 256, 0, stream>>>(xz, u_bf, xdbl, A_log, D_skip, hlast);
    }

    // 7. out_proj (bf16 MFMA) + residual + mask -> d_out
    gemm_bf16<2><<<(DMODEL / 128) * (M / 128), 256, 0, stream>>>(
        u_bf, DINNER, w_out, DINNER, out, DMODEL, M, DMODEL, DINNER, DMODEL / 128,
        nullptr, hs, lengths);
}

// Round 5
// 498.549 us; speedup vs baseline: 6.4390x; 1.0665x over previous
//
#include <hip/hip_runtime.h>
#include <cstdint>
#include <cstddef>

#define LSEQ 2048
#define NB   4
#define DMODEL 1024
#define DINNER 2048
#define NST  16
#define TT   64    // scan LDS time-tile
#define CH   128   // scan chunk length
#define SCH  (LSEQ / CH)   // 16 chunks

typedef short bf16x8 __attribute__((ext_vector_type(8)));
typedef float f32x4  __attribute__((ext_vector_type(4)));

__device__ __forceinline__ float siluf(float x) { return x / (1.f + __expf(-x)); }

__device__ __forceinline__ unsigned short f2bf(float f) {
    unsigned u = __float_as_uint(f);
    u += 0x7FFF + ((u >> 16) & 1);     // round-to-nearest-even
    return (unsigned short)(u >> 16);
}
__device__ __forceinline__ float bf2f(unsigned short h) {
    return __uint_as_float(((unsigned)h) << 16);
}
__device__ __forceinline__ void gload_lds16(const void* g, void* l) {
    __builtin_amdgcn_global_load_lds(
        (const __attribute__((address_space(1))) unsigned int*)g,
        (__attribute__((address_space(3))) unsigned int*)l, 16, 0, 0);
}

template <int CTRL>
__device__ __forceinline__ float dpp_ror(float v) {
    return __int_as_float(__builtin_amdgcn_update_dpp(
        0, __float_as_int(v), CTRL, 0xf, 0xf, false));
}

// ---------------- fused RMSNorm + bf16 convert ----------------
__global__ __launch_bounds__(256) void rmsnorm_cvt_k(const float* __restrict__ x,
                                                     const float* __restrict__ nw,
                                                     unsigned short* __restrict__ o) {
    int row = blockIdx.x, t = threadIdx.x;
    float4 v = ((const float4*)(x + (size_t)row * DMODEL))[t];
    float s = v.x * v.x + v.y * v.y + v.z * v.z + v.w * v.w;
#pragma unroll
    for (int m = 32; m >= 1; m >>= 1) s += __shfl_xor(s, m);
    __shared__ float wsum[4];
    __shared__ float sinv;
    if ((t & 63) == 0) wsum[t >> 6] = s;
    __syncthreads();
    if (t == 0) {
        float tot = wsum[0] + wsum[1] + wsum[2] + wsum[3];
        sinv = rsqrtf(tot * (1.f / (float)DMODEL) + 1e-6f);
    }
    __syncthreads();
    float iv = sinv;
    float4 w = ((const float4*)nw)[t];
    ushort4 ov;
    ov.x = f2bf(v.x * iv * w.x); ov.y = f2bf(v.y * iv * w.y);
    ov.z = f2bf(v.z * iv * w.z); ov.w = f2bf(v.w * iv * w.w);
    ((ushort4*)(o + (size_t)row * DMODEL))[t] = ov;
}

// ---------------- flat f32 -> bf16 ----------------
__global__ __launch_bounds__(256) void cvt_bf_k(const float* __restrict__ src,
                                                unsigned short* __restrict__ dst, int n4) {
    int i = blockIdx.x * 256 + threadIdx.x;
    if (i < n4) {
        float4 v = ((const float4*)src)[i];
        ushort4 o;
        o.x = f2bf(v.x); o.y = f2bf(v.y); o.z = f2bf(v.z); o.w = f2bf(v.w);
        ((ushort4*)dst)[i] = o;
    }
}

// ---------------- extract dt_r (cols 0..63 of xdbl) -> bf16 ----------------
__global__ __launch_bounds__(256) void dtr_cvt_k(const float* __restrict__ xdbl,
                                                 unsigned short* __restrict__ dtr) {
    int idx = blockIdx.x * 256 + threadIdx.x;    // 131072 total
    int row = idx >> 4, c4 = (idx & 15) << 2;
    float4 v = *(const float4*)(xdbl + (size_t)row * 96 + c4);
    ushort4 o;
    o.x = f2bf(v.x); o.y = f2bf(v.y); o.z = f2bf(v.z); o.w = f2bf(v.w);
    *(ushort4*)(dtr + (size_t)row * 64 + c4) = o;
}

// ---------------- bf16 MFMA NT GEMM: C(MxN,f32) = A(MxK) * W(NxK)^T ----------------
template <int EPI>
__global__ __launch_bounds__(256) void gemm_bf16(
    const unsigned short* __restrict__ A, int lda,
    const unsigned short* __restrict__ W, int ldw,
    float* __restrict__ C, int ldc,
    int M, int N, int K, int nbx,
    const float* __restrict__ bias,
    const float* __restrict__ residual,
    const int* __restrict__ lengths) {
    __shared__ __align__(16) unsigned short As[128 * 64];
    __shared__ __align__(16) unsigned short Bs[128 * 64];
    const int nwg = gridDim.x;
    const int bid = blockIdx.x;
    const int cpx = nwg >> 3;                       // nwg % 8 == 0 for all launches
    const int swz = (bid & 7) * cpx + (bid >> 3);
    const int bx = swz % nbx, by = swz / nbx;
    const int row0 = by * 128, col0 = bx * 128;
    const int t = threadIdx.x;
    const int lane = t & 63;
    const int w = t >> 6;
    const int wr = w >> 1, wc = w & 1;

    f32x4 acc[4][4];
#pragma unroll
    for (int m = 0; m < 4; ++m)
#pragma unroll
        for (int n = 0; n < 4; ++n) acc[m][n] = f32x4{0.f, 0.f, 0.f, 0.f};

    const int rA = lane & 15;
    const int kH = (lane >> 4) << 3;

    for (int k0 = 0; k0 < K; k0 += 64) {
#pragma unroll
        for (int it = 0; it < 4; ++it) {
            int c = it * 256 + t;
            int r = c >> 3, cc = (c & 7) << 3;
            gload_lds16(A + (size_t)(row0 + r) * lda + k0 + cc, &As[c << 3]);
            int wrow = col0 + r; if (wrow >= N) wrow = N - 1;   // clamp (x_proj N=96)
            gload_lds16(W + (size_t)wrow * ldw + k0 + cc, &Bs[c << 3]);
        }
        __syncthreads();
#pragma unroll
        for (int ks = 0; ks < 2; ++ks) {
            const int kk = ks * 32 + kH;
            bf16x8 af[4], bfr[4];
#pragma unroll
            for (int m = 0; m < 4; ++m)
                af[m] = *(const bf16x8*)&As[(wr * 64 + m * 16 + rA) * 64 + kk];
#pragma unroll
            for (int n = 0; n < 4; ++n)
                bfr[n] = *(const bf16x8*)&Bs[(wc * 64 + n * 16 + rA) * 64 + kk];
#pragma unroll
            for (int m = 0; m < 4; ++m)
#pragma unroll
                for (int n = 0; n < 4; ++n)
                    acc[m][n] = __builtin_amdgcn_mfma_f32_16x16x32_bf16(
                        af[m], bfr[n], acc[m][n], 0, 0, 0);
        }
        __syncthreads();
    }
    const int cl = lane & 15, rg = lane >> 4;
#pragma unroll
    for (int m = 0; m < 4; ++m) {
#pragma unroll
        for (int j = 0; j < 4; ++j) {
            const int row = row0 + wr * 64 + m * 16 + rg * 4 + j;
            float msk = 1.f;
            if (EPI != 0) {
                int bb = row >> 11, ll = row & (LSEQ - 1);
                msk = (ll < lengths[bb]) ? 1.f : 0.f;
            }
#pragma unroll
            for (int n = 0; n < 4; ++n) {
                const int col = col0 + wc * 64 + n * 16 + cl;
                if (col < N) {
                    float v = acc[m][n][j];
                    if (EPI == 1) {
                        v += bias[col];
                        v = (v > 20.f) ? v : log1pf(__expf(v));
                        v *= msk;
                    } else if (EPI == 2) {
                        v = residual[(size_t)row * N + col] + msk * v;
                    }
                    C[(size_t)row * ldc + col] = v;
                }
            }
        }
    }
}

// ---------------- causal depthwise conv (K=4) + SiLU + mask -> bf16 ----------------
__global__ __launch_bounds__(256) void conv_silu_k(const float* __restrict__ xz,
                                                   const float* __restrict__ cw,
                                                   const int* __restrict__ lengths,
                                                   unsigned short* __restrict__ u) {
    const int g = blockIdx.x;              // NB * 512
    const int b = g >> 9;
    const int rem = g & 511;
    const int l0 = (rem >> 1) << 3;
    const int d4 = (rem & 1) * 1024 + threadIdx.x * 4;
    const int len = lengths[b];
    float4 wq[4];
#pragma unroll
    for (int c = 0; c < 4; ++c) wq[c] = *(const float4*)(cw + 4 * (d4 + c));
    const size_t rb = (size_t)b * LSEQ;
    const float4 zero4 = {0.f, 0.f, 0.f, 0.f};
    float4 xm3 = (l0 - 3 >= 0 && l0 - 3 < len) ? *(const float4*)(xz + (rb + l0 - 3) * 4096 + d4) : zero4;
    float4 xm2 = (l0 - 2 >= 0 && l0 - 2 < len) ? *(const float4*)(xz + (rb + l0 - 2) * 4096 + d4) : zero4;
    float4 xm1 = (l0 - 1 >= 0 && l0 - 1 < len) ? *(const float4*)(xz + (rb + l0 - 1) * 4096 + d4) : zero4;
#pragma unroll
    for (int i = 0; i < 8; ++i) {
        const int l = l0 + i;
        const bool act = l < len;
        float4 x0 = act ? *(const float4*)(xz + (rb + l) * 4096 + d4) : zero4;
        float a0 = wq[0].x * xm3.x + wq[0].y * xm2.x + wq[0].z * xm1.x + wq[0].w * x0.x;
        float a1 = wq[1].x * xm3.y + wq[1].y * xm2.y + wq[1].z * xm1.y + wq[1].w * x0.y;
        float a2 = wq[2].x * xm3.z + wq[2].y * xm2.z + wq[2].z * xm1.z + wq[2].w * x0.z;
        float a3 = wq[3].x * xm3.w + wq[3].y * xm2.w + wq[3].z * xm1.w + wq[3].w * x0.w;
        ushort4 ov;
        ov.x = f2bf(act ? siluf(a0) : 0.f);
        ov.y = f2bf(act ? siluf(a1) : 0.f);
        ov.z = f2bf(act ? siluf(a2) : 0.f);
        ov.w = f2bf(act ? siluf(a3) : 0.f);
        *(ushort4*)(u + (rb + l) * DINNER + d4) = ov;
        xm3 = xm2; xm2 = xm1; xm1 = x0;
    }
}

// ---------------- scan phase 1: per-chunk local scan (h_in = 0) ----------------
// grid = NB * (DINNER/16) * SCH; block = 16ch x 16n
// out: hloc[bid*256+t] (chunk-final local state), sumd[bid*16+ch] (sum of delta)
__global__ __launch_bounds__(256) void scan_p1(const float* __restrict__ xz,
                                               const unsigned short* __restrict__ uy,
                                               const float* __restrict__ xdbl,
                                               const float* __restrict__ A_log,
                                               float* __restrict__ hloc,
                                               float* __restrict__ sumd) {
    __shared__ float2 sDU[TT][18];   // {delta, delta*u}; 144B row stride
    __shared__ float  sB[TT][20];    // 80B row stride
    const int t = threadIdx.x;
    const int bid = blockIdx.x;
    const int s = bid & (SCH - 1);
    const int bd = bid >> 4;
    const int b = bd >> 7;
    const int d0 = (bd & 127) << 4;
    const int lr = t >> 2, lq = (t & 3) << 2;
    const int ch = t >> 4, n = t & 15;
    const int d = d0 + ch;
    const float Av2 = -__expf(A_log[d * NST + n]) * 1.44269504f;
    float h = 0.f, sd = 0.f;
    const size_t base = (size_t)b * LSEQ + (size_t)s * CH;

    for (int l0 = 0; l0 < CH; l0 += TT) {
        const size_t row = base + l0 + lr;
        float4 dv = *(const float4*)(xz + row * 4096 + d0 + lq);
        ushort4 uv = *(const ushort4*)(uy + row * DINNER + d0 + lq);
        float4 bv = *(const float4*)(xdbl + row * 96 + 64 + lq);
        float4 w0 = {dv.x, dv.x * bf2f(uv.x), dv.y, dv.y * bf2f(uv.y)};
        float4 w1 = {dv.z, dv.z * bf2f(uv.z), dv.w, dv.w * bf2f(uv.w)};
        *(float4*)&sDU[lr][lq]     = w0;
        *(float4*)&sDU[lr][lq + 2] = w1;
        *(float4*)&sB[lr][lq] = bv;
        __syncthreads();
#pragma unroll 16
        for (int r = 0; r < TT; ++r) {
            float2 ddu = sDU[r][ch];
            float Bn = sB[r][n];
            float dA = __builtin_amdgcn_exp2f(ddu.x * Av2);
            h = fmaf(dA, h, ddu.y * Bn);
            sd += ddu.x;
        }
        __syncthreads();
    }
    hloc[(size_t)bid * 256 + t] = h;
    if (n == 0) sumd[bid * 16 + ch] = sd;
}

// ---------------- scan phase 2: sequential chunk fix-up + h_last ----------------
// grid = NB * (DINNER/16); block (ch,n)
__global__ __launch_bounds__(256) void scan_p2(const float* __restrict__ hloc,
                                               const float* __restrict__ sumd,
                                               const float* __restrict__ A_log,
                                               float* __restrict__ hin,
                                               float* __restrict__ out_h) {
    const int t = threadIdx.x;
    const int bd = blockIdx.x;
    const int b = bd >> 7;
    const int d = ((bd & 127) << 4) + (t >> 4);
    const int n = t & 15;
    const float Av2 = -__expf(A_log[d * NST + n]) * 1.44269504f;
    float h = 0.f;
#pragma unroll
    for (int s = 0; s < SCH; ++s) {
        const size_t idx = ((size_t)bd * SCH + s) * 256 + t;
        hin[idx] = h;
        float P = __builtin_amdgcn_exp2f(Av2 * sumd[(bd * SCH + s) * 16 + (t >> 4)]);
        h = fmaf(P, h, hloc[idx]);
    }
    out_h[((size_t)(b * DINNER + d)) * NST + n] = h;
}

// ---------------- scan phase 3: replay chunk from h_in, produce gated y ----------------
__global__ __launch_bounds__(256) void scan_p3(const float* __restrict__ xz,
                                               unsigned short* uy,
                                               const float* __restrict__ xdbl,
                                               const float* __restrict__ A_log,
                                               const float* __restrict__ D_skip,
                                               const float* __restrict__ hin) {
    __shared__ float2 sDU[TT][18];   // {delta, delta*u}
    __shared__ float2 sBC[TT][18];   // {B, C}
    __shared__ float  sY[TT][16];
    const int t = threadIdx.x;
    const int bid = blockIdx.x;
    const int s = bid & (SCH - 1);
    const int bd = bid >> 4;
    const int b = bd >> 7;
    const int d0 = (bd & 127) << 4;
    const int lr = t >> 2, lq = (t & 3) << 2;
    const int ch = t >> 4, n = t & 15;
    const int d = d0 + ch;
    const float Av2 = -__expf(A_log[d * NST + n]) * 1.44269504f;
    const float4 Dv4 = *(const float4*)(D_skip + d0 + lq);
    float h = hin[(size_t)bid * 256 + t];
    const size_t base = (size_t)b * LSEQ + (size_t)s * CH;

    for (int l0 = 0; l0 < CH; l0 += TT) {
        const size_t row = base + l0 + lr;
        float4 dv = *(const float4*)(xz + row * 4096 + d0 + lq);
        ushort4 uv = *(const ushort4*)(uy + row * DINNER + d0 + lq);
        float4 zv = *(const float4*)(xz + row * 4096 + DINNER + d0 + lq);
        float4 bv = *(const float4*)(xdbl + row * 96 + 64 + lq);
        float4 cv = *(const float4*)(xdbl + row * 96 + 80 + lq);
        const float uf0 = bf2f(uv.x), uf1 = bf2f(uv.y), uf2 = bf2f(uv.z), uf3 = bf2f(uv.w);
        float4 w0 = {dv.x, dv.x * uf0, dv.y, dv.y * uf1};
        float4 w1 = {dv.z, dv.z * uf2, dv.w, dv.w * uf3};
        *(float4*)&sDU[lr][lq]     = w0;
        *(float4*)&sDU[lr][lq + 2] = w1;
        float4 e0 = {bv.x, cv.x, bv.y, cv.y};
        float4 e1 = {bv.z, cv.z, bv.w, cv.w};
        *(float4*)&sBC[lr][lq]     = e0;
        *(float4*)&sBC[lr][lq + 2] = e1;
        __syncthreads();

#pragma unroll 16
        for (int r = 0; r < TT; ++r) {
            float2 ddu = sDU[r][ch];
            float2 bc  = sBC[r][n];
            float dA = __builtin_amdgcn_exp2f(ddu.x * Av2);
            h = fmaf(dA, h, ddu.y * bc.x);
            float p = h * bc.y;
            p += dpp_ror<0x128>(p);
            p += dpp_ror<0x124>(p);
            p += dpp_ror<0x122>(p);
            p += dpp_ror<0x121>(p);
            if (n == 0) sY[r][ch] = p;
        }
        __syncthreads();

        float4 yv = *(const float4*)&sY[lr][lq];
        ushort4 ov;
        ov.x = f2bf(fmaf(uf0, Dv4.x, yv.x) * siluf(zv.x));
        ov.y = f2bf(fmaf(uf1, Dv4.y, yv.y) * siluf(zv.y));
        ov.z = f2bf(fmaf(uf2, Dv4.z, yv.z) * siluf(zv.z));
        ov.w = f2bf(fmaf(uf3, Dv4.w, yv.w) * siluf(zv.w));
        *(ushort4*)(uy + row * DINNER + d0 + lq) = ov;
        __syncthreads();
    }
}

extern "C" void kernel_launch(void* const* d_in, const int* in_sizes, int n_in,
                              void* d_out, int out_size, void* d_ws, size_t ws_size,
                              hipStream_t stream) {
    const float* hs        = (const float*)d_in[0];
    const int*   lengths   = (const int*)d_in[1];
    const float* norm_w    = (const float*)d_in[2];
    const float* in_proj_w = (const float*)d_in[3];
    const float* conv_w    = (const float*)d_in[4];
    const float* x_proj_w  = (const float*)d_in[5];
    const float* dt_proj_w = (const float*)d_in[6];
    const float* dt_proj_b = (const float*)d_in[7];
    const float* A_log     = (const float*)d_in[8];
    const float* D_skip    = (const float*)d_in[9];
    const float* out_proj_w= (const float*)d_in[10];

    float* out = (float*)d_out;
    float* ws  = (float*)d_ws;

    const int M = NB * LSEQ;                                            // 8192
    float* xz = ws;                                                     // 8192x4096 f32 (128MB)
    unsigned short* u_bf = (unsigned short*)(xz + (size_t)M * 4096);    // 8192x2048 bf16 (32MB)
    float* xdbl = (float*)(u_bf + (size_t)M * DINNER);                  // 8192x96 f32 (3MB)
    unsigned short* w_in  = (unsigned short*)(xdbl + (size_t)M * 96);   // 4096x1024 (8MB)
    unsigned short* w_out = w_in + (size_t)4096 * 1024;                 // 1024x2048 (4MB)
    unsigned short* w_x   = w_out + (size_t)1024 * 2048;                // 96x2048
    unsigned short* w_dt  = w_x + (size_t)96 * 2048;                    // 2048x64
    unsigned short* dtr   = w_dt + (size_t)2048 * 64;                   // 8192x64 (1MB)
    float* hin            = (float*)(dtr + (size_t)M * 64);             // 8192x256 f32 (8MB)
    unsigned short* xn_bf = u_bf;          // alias: dead once conv overwrites it
    float* hloc = (float*)w_in;            // alias: w_in dead after in_proj (8MB = exact fit)
    float* sumd = (float*)dtr;             // alias: dtr dead after dt_proj (needs 512KB of 1MB)

    // 1. fused RMSNorm->bf16 + weight conversions
    rmsnorm_cvt_k<<<M, 256, 0, stream>>>(hs, norm_w, xn_bf);
    cvt_bf_k<<<4096, 256, 0, stream>>>(in_proj_w, w_in, 1048576);
    cvt_bf_k<<<2048, 256, 0, stream>>>(out_proj_w, w_out, 524288);
    cvt_bf_k<<<192, 256, 0, stream>>>(x_proj_w, w_x, 49152);
    cvt_bf_k<<<128, 256, 0, stream>>>(dt_proj_w, w_dt, 32768);

    // 2. in_proj (bf16 MFMA): xz = xn @ in_proj_w^T   (8192x4096, K=1024)
    gemm_bf16<0><<<(4096 / 128) * (M / 128), 256, 0, stream>>>(
        xn_bf, DMODEL, w_in, DMODEL, xz, 4096, M, 4096, DMODEL, 4096 / 128,
        nullptr, nullptr, nullptr);

    // 3. causal depthwise conv + silu + mask -> u (bf16)
    conv_silu_k<<<NB * 512, 256, 0, stream>>>(xz, conv_w, lengths, u_bf);

    // 4. x_proj (bf16 MFMA): xdbl = u @ x_proj_w^T  (8192x96, K=2048)
    gemm_bf16<0><<<1 * (M / 128), 256, 0, stream>>>(
        u_bf, DINNER, w_x, DINNER, xdbl, 96, M, 96, DINNER, 1,
        nullptr, nullptr, nullptr);

    // 5. dt_r -> bf16, then dt_proj (bf16 MFMA) + softplus + mask: delta -> xz cols 0..2047
    dtr_cvt_k<<<512, 256, 0, stream>>>(xdbl, dtr);
    gemm_bf16<1><<<(DINNER / 128) * (M / 128), 256, 0, stream>>>(
        dtr, 64, w_dt, 64, xz, 4096, M, DINNER, 64, DINNER / 128,
        dt_proj_b, nullptr, lengths);

    // 6. chunked selective scan (3 phases); h_last -> tail of d_out
    {
        float* hlast = out + (size_t)M * DMODEL;
        const int nbd = NB * (DINNER / 16);                 // 512
        scan_p1<<<nbd * SCH, 256, 0, stream>>>(xz, u_bf, xdbl, A_log, hloc, sumd);
        scan_p2<<<nbd, 256, 0, stream>>>(hloc, sumd, A_log, hin, hlast);
        scan_p3<<<nbd * SCH, 256, 0, stream>>>(xz, u_bf, xdbl, A_log, D_skip, hin);
    }

    // 7. out_proj (bf16 MFMA) + residual + mask -> d_out
    gemm_bf16<2><<<(DMODEL / 128) * (M / 128), 256, 0, stream>>>(
        u_bf, DINNER, w_out, DINNER, out, DMODEL, M, DMODEL, DINNER, DMODEL / 128,
        nullptr, hs, lengths);
}

// Round 7
// 465.981 us; speedup vs baseline: 6.8890x; 1.0699x over previous
//
#include <hip/hip_runtime.h>
#include <cstdint>
#include <cstddef>

#define LSEQ 2048
#define NB   4
#define DMODEL 1024
#define DINNER 2048
#define NST  16
#define TT   64    // scan LDS time-tile
#define CH   128   // scan chunk length == GEMM tile height
#define SCH  (LSEQ / CH)   // 16 chunks

typedef short bf16x8 __attribute__((ext_vector_type(8)));
typedef float f32x4  __attribute__((ext_vector_type(4)));

__device__ __forceinline__ float siluf(float x) { return x / (1.f + __expf(-x)); }

__device__ __forceinline__ unsigned short f2bf(float f) {
    unsigned u = __float_as_uint(f);
    u += 0x7FFF + ((u >> 16) & 1);     // round-to-nearest-even
    return (unsigned short)(u >> 16);
}
__device__ __forceinline__ float bf2f(unsigned short h) {
    return __uint_as_float(((unsigned)h) << 16);
}
__device__ __forceinline__ void gload_lds16(const void* g, void* l) {
    __builtin_amdgcn_global_load_lds(
        (const __attribute__((address_space(1))) unsigned int*)g,
        (__attribute__((address_space(3))) unsigned int*)l, 16, 0, 0);
}

template <int CTRL>
__device__ __forceinline__ float dpp_ror(float v) {
    return __int_as_float(__builtin_amdgcn_update_dpp(
        0, __float_as_int(v), CTRL, 0xf, 0xf, false));
}

// ---------------- fused RMSNorm + bf16 convert ----------------
__global__ __launch_bounds__(256) void rmsnorm_cvt_k(const float* __restrict__ x,
                                                     const float* __restrict__ nw,
                                                     unsigned short* __restrict__ o) {
    int row = blockIdx.x, t = threadIdx.x;
    float4 v = ((const float4*)(x + (size_t)row * DMODEL))[t];
    float s = v.x * v.x + v.y * v.y + v.z * v.z + v.w * v.w;
#pragma unroll
    for (int m = 32; m >= 1; m >>= 1) s += __shfl_xor(s, m);
    __shared__ float wsum[4];
    __shared__ float sinv;
    if ((t & 63) == 0) wsum[t >> 6] = s;
    __syncthreads();
    if (t == 0) {
        float tot = wsum[0] + wsum[1] + wsum[2] + wsum[3];
        sinv = rsqrtf(tot * (1.f / (float)DMODEL) + 1e-6f);
    }
    __syncthreads();
    float iv = sinv;
    float4 w = ((const float4*)nw)[t];
    ushort4 ov;
    ov.x = f2bf(v.x * iv * w.x); ov.y = f2bf(v.y * iv * w.y);
    ov.z = f2bf(v.z * iv * w.z); ov.w = f2bf(v.w * iv * w.w);
    ((ushort4*)(o + (size_t)row * DMODEL))[t] = ov;
}

// ---------------- fused weight conversions (4 matrices, 1 launch) ----------------
__global__ __launch_bounds__(256) void cvt_all_k(const float* __restrict__ s0, const float* __restrict__ s1,
                                                 const float* __restrict__ s2, const float* __restrict__ s3,
                                                 unsigned short* __restrict__ q0, unsigned short* __restrict__ q1,
                                                 unsigned short* __restrict__ q2, unsigned short* __restrict__ q3) {
    int i = blockIdx.x * 256 + threadIdx.x;
    const float* s; unsigned short* d; int off;
    if (i < 1048576)       { s = s0; d = q0; off = i; }
    else if (i < 1572864)  { s = s1; d = q1; off = i - 1048576; }
    else if (i < 1622016)  { s = s2; d = q2; off = i - 1572864; }
    else if (i < 1654784)  { s = s3; d = q3; off = i - 1622016; }
    else return;
    float4 v = ((const float4*)s)[off];
    ushort4 o;
    o.x = f2bf(v.x); o.y = f2bf(v.y); o.z = f2bf(v.z); o.w = f2bf(v.w);
    ((ushort4*)d)[off] = o;
}

// ---------------- bf16 MFMA NT GEMM with row-tile skip ----------------
// EPI 0: split f32 store: col<2048 -> Cv (ur), col>=2048 -> C2 (z)   (in_proj)
// EPI 1: softplus(acc+bias)*mask -> f32 store                        (dt_proj)
// EPI 2: residual + mask*acc -> f32; skipped tiles copy residual     (out_proj)
// EPI 3: col<64 -> bf16 aux (dtr); 64<=col<96 -> f32 Cv (xdbl, ld96) (x_proj)
template <int EPI>
__global__ __launch_bounds__(256) void gemm_bf16(
    const unsigned short* __restrict__ A, int lda,
    const unsigned short* __restrict__ W, int ldw,
    void* __restrict__ Cv, float* __restrict__ C2, int ldc,
    int M, int N, int K, int nbx,
    const float* __restrict__ bias,
    const float* __restrict__ residual,
    unsigned short* __restrict__ aux,
    const int* __restrict__ lengths) {
    __shared__ __align__(16) unsigned short As[128 * 64];
    __shared__ __align__(16) unsigned short Bs[128 * 64];
    const int nwg = gridDim.x;
    const int bid = blockIdx.x;
    const int cpx = nwg >> 3;                       // nwg % 8 == 0 for all launches
    const int swz = (bid & 7) * cpx + (bid >> 3);
    const int bx = swz % nbx, by = swz / nbx;
    const int row0 = by * 128, col0 = bx * 128;
    const int t = threadIdx.x;

    // row-tile skip: rows [row0,row0+128) all masked -> outputs never consumed
    const int len0 = lengths[row0 >> 11];
    if ((row0 & (LSEQ - 1)) >= len0) {
        if (EPI == 2) {
            float* C = (float*)Cv;
#pragma unroll
            for (int i = 0; i < 16; ++i) {
                int lin = i * 256 + t;                  // 4096 float4 = 128x128
                int r = lin >> 5, c = (lin & 31) << 2;
                *(float4*)(C + (size_t)(row0 + r) * ldc + col0 + c) =
                    *(const float4*)(residual + (size_t)(row0 + r) * ldc + col0 + c);
            }
        }
        return;
    }

    const int lane = t & 63;
    const int w = t >> 6;
    const int wr = w >> 1, wc = w & 1;

    f32x4 acc[4][4];
#pragma unroll
    for (int m = 0; m < 4; ++m)
#pragma unroll
        for (int n = 0; n < 4; ++n) acc[m][n] = f32x4{0.f, 0.f, 0.f, 0.f};

    const int rA = lane & 15;
    const int kH = (lane >> 4) << 3;

    for (int k0 = 0; k0 < K; k0 += 64) {
#pragma unroll
        for (int it = 0; it < 4; ++it) {
            int c = it * 256 + t;
            int r = c >> 3, cc = (c & 7) << 3;
            gload_lds16(A + (size_t)(row0 + r) * lda + k0 + cc, &As[c << 3]);
            int wrow = col0 + r; if (wrow >= N) wrow = N - 1;   // clamp (x_proj N=96)
            gload_lds16(W + (size_t)wrow * ldw + k0 + cc, &Bs[c << 3]);
        }
        __syncthreads();
#pragma unroll
        for (int ks = 0; ks < 2; ++ks) {
            const int kk = ks * 32 + kH;
            bf16x8 af[4], bfr[4];
#pragma unroll
            for (int m = 0; m < 4; ++m)
                af[m] = *(const bf16x8*)&As[(wr * 64 + m * 16 + rA) * 64 + kk];
#pragma unroll
            for (int n = 0; n < 4; ++n)
                bfr[n] = *(const bf16x8*)&Bs[(wc * 64 + n * 16 + rA) * 64 + kk];
#pragma unroll
            for (int m = 0; m < 4; ++m)
#pragma unroll
                for (int n = 0; n < 4; ++n)
                    acc[m][n] = __builtin_amdgcn_mfma_f32_16x16x32_bf16(
                        af[m], bfr[n], acc[m][n], 0, 0, 0);
        }
        __syncthreads();
    }
    const int cl = lane & 15, rg = lane >> 4;
#pragma unroll
    for (int m = 0; m < 4; ++m) {
#pragma unroll
        for (int j = 0; j < 4; ++j) {
            const int row = row0 + wr * 64 + m * 16 + rg * 4 + j;
            float msk = 1.f;
            if (EPI == 1 || EPI == 2) {
                msk = ((row & (LSEQ - 1)) < len0) ? 1.f : 0.f;
            }
#pragma unroll
            for (int n = 0; n < 4; ++n) {
                const int col = col0 + wc * 64 + n * 16 + cl;
                float v = acc[m][n][j];
                if (EPI == 0) {
                    if (col < DINNER) ((float*)Cv)[(size_t)row * DINNER + col] = v;
                    else              C2[(size_t)row * DINNER + col - DINNER] = v;
                } else if (EPI == 1) {
                    v += bias[col];
                    v = (v > 20.f) ? v : log1pf(__expf(v));
                    ((float*)Cv)[(size_t)row * ldc + col] = v * msk;
                } else if (EPI == 2) {
                    ((float*)Cv)[(size_t)row * ldc + col] =
                        residual[(size_t)row * ldc + col] + msk * v;
                } else {  // EPI 3
                    if (col < 64) aux[(size_t)row * 64 + col] = f2bf(v);
                    else if (col < 96) ((float*)Cv)[(size_t)row * 96 + col] = v;
                }
            }
        }
    }
}

// ---------------- causal depthwise conv (K=4) + SiLU + mask -> bf16 ----------------
// fully-masked blocks write exact zeros (no loads) so u == 0 at all masked rows
__global__ __launch_bounds__(256) void conv_silu_k(const float* __restrict__ ur,
                                                   const float* __restrict__ cw,
                                                   const int* __restrict__ lengths,
                                                   unsigned short* __restrict__ u) {
    const int g = blockIdx.x;              // NB * 512
    const int b = g >> 9;
    const int rem = g & 511;
    const int l0 = (rem >> 1) << 3;
    const int d4 = (rem & 1) * 1024 + threadIdx.x * 4;
    const int len = lengths[b];
    const size_t rb = (size_t)b * LSEQ;
    if (l0 >= len) {
        ushort4 z4 = {0, 0, 0, 0};
#pragma unroll
        for (int i = 0; i < 8; ++i)
            *(ushort4*)(u + (rb + l0 + i) * DINNER + d4) = z4;
        return;
    }
    float4 wq[4];
#pragma unroll
    for (int c = 0; c < 4; ++c) wq[c] = *(const float4*)(cw + 4 * (d4 + c));
    const float4 zero4 = {0.f, 0.f, 0.f, 0.f};
    float4 xm3 = (l0 - 3 >= 0 && l0 - 3 < len) ? *(const float4*)(ur + (rb + l0 - 3) * DINNER + d4) : zero4;
    float4 xm2 = (l0 - 2 >= 0 && l0 - 2 < len) ? *(const float4*)(ur + (rb + l0 - 2) * DINNER + d4) : zero4;
    float4 xm1 = (l0 - 1 >= 0 && l0 - 1 < len) ? *(const float4*)(ur + (rb + l0 - 1) * DINNER + d4) : zero4;
#pragma unroll
    for (int i = 0; i < 8; ++i) {
        const int l = l0 + i;
        const bool act = l < len;
        float4 x0 = act ? *(const float4*)(ur + (rb + l) * DINNER + d4) : zero4;
        float a0 = wq[0].x * xm3.x + wq[0].y * xm2.x + wq[0].z * xm1.x + wq[0].w * x0.x;
        float a1 = wq[1].x * xm3.y + wq[1].y * xm2.y + wq[1].z * xm1.y + wq[1].w * x0.y;
        float a2 = wq[2].x * xm3.z + wq[2].y * xm2.z + wq[2].z * xm1.z + wq[2].w * x0.z;
        float a3 = wq[3].x * xm3.w + wq[3].y * xm2.w + wq[3].z * xm1.w + wq[3].w * x0.w;
        ushort4 ov;
        ov.x = f2bf(act ? siluf(a0) : 0.f);
        ov.y = f2bf(act ? siluf(a1) : 0.f);
        ov.z = f2bf(act ? siluf(a2) : 0.f);
        ov.w = f2bf(act ? siluf(a3) : 0.f);
        *(ushort4*)(u + (rb + l) * DINNER + d4) = ov;
        xm3 = xm2; xm2 = xm1; xm1 = x0;
    }
}

// ---------------- scan phase 1: per-chunk local scan (h_in = 0) ----------------
__global__ __launch_bounds__(256) void scan_p1(const float* __restrict__ dlt,
                                               const unsigned short* __restrict__ uy,
                                               const float* __restrict__ xdbl,
                                               const float* __restrict__ A_log,
                                               const int* __restrict__ lengths,
                                               float* __restrict__ hloc,
                                               float* __restrict__ sumd) {
    __shared__ float2 sDU[TT][18];   // {delta, delta*u}; padded stride
    __shared__ float  sB[TT][20];
    const int t = threadIdx.x;
    const int bid = blockIdx.x;
    const int s = bid & (SCH - 1);
    const int bd = bid >> 4;
    const int b = bd >> 7;
    const int d0 = (bd & 127) << 4;
    const int n = t & 15, ch = t >> 4;
    if (s * CH >= lengths[b]) {          // fully masked chunk: exact identity
        hloc[(size_t)bid * 256 + t] = 0.f;
        if (n == 0) sumd[bid * 16 + ch] = 0.f;
        return;
    }
    const int lr = t >> 2, lq = (t & 3) << 2;
    const int d = d0 + ch;
    const float Av2 = -__expf(A_log[d * NST + n]) * 1.44269504f;
    float h = 0.f, sd = 0.f;
    const size_t base = (size_t)b * LSEQ + (size_t)s * CH;

    for (int l0 = 0; l0 < CH; l0 += TT) {
        const size_t row = base + l0 + lr;
        float4 dv = *(const float4*)(dlt + row * DINNER + d0 + lq);
        ushort4 uv = *(const ushort4*)(uy + row * DINNER + d0 + lq);
        float4 bv = *(const float4*)(xdbl + row * 96 + 64 + lq);
        float4 w0 = {dv.x, dv.x * bf2f(uv.x), dv.y, dv.y * bf2f(uv.y)};
        float4 w1 = {dv.z, dv.z * bf2f(uv.z), dv.w, dv.w * bf2f(uv.w)};
        *(float4*)&sDU[lr][lq]     = w0;
        *(float4*)&sDU[lr][lq + 2] = w1;
        *(float4*)&sB[lr][lq] = bv;
        __syncthreads();
#pragma unroll 16
        for (int r = 0; r < TT; ++r) {
            float2 ddu = sDU[r][ch];
            float Bn = sB[r][n];
            float dA = __builtin_amdgcn_exp2f(ddu.x * Av2);
            h = fmaf(dA, h, ddu.y * Bn);
            sd += ddu.x;
        }
        __syncthreads();
    }
    hloc[(size_t)bid * 256 + t] = h;
    if (n == 0) sumd[bid * 16 + ch] = sd;
}

// ---------------- scan phase 2: sequential chunk fix-up + h_last ----------------
__global__ __launch_bounds__(256) void scan_p2(const float* __restrict__ hloc,
                                               const float* __restrict__ sumd,
                                               const float* __restrict__ A_log,
                                               float* __restrict__ hin,
                                               float* __restrict__ out_h) {
    const int t = threadIdx.x;
    const int bd = blockIdx.x;
    const int b = bd >> 7;
    const int d = ((bd & 127) << 4) + (t >> 4);
    const int n = t & 15;
    const float Av2 = -__expf(A_log[d * NST + n]) * 1.44269504f;
    float h = 0.f;
#pragma unroll
    for (int s = 0; s < SCH; ++s) {
        const size_t idx = ((size_t)bd * SCH + s) * 256 + t;
        hin[idx] = h;
        float P = __builtin_amdgcn_exp2f(Av2 * sumd[(bd * SCH + s) * 16 + (t >> 4)]);
        h = fmaf(P, h, hloc[idx]);
    }
    out_h[((size_t)(b * DINNER + d)) * NST + n] = h;
}

// ---------------- scan phase 3: replay chunk from h_in, produce gated y ----------------
__global__ __launch_bounds__(256) void scan_p3(const float* __restrict__ dlt,
                                               const float* __restrict__ zb,
                                               unsigned short* uy,
                                               const float* __restrict__ xdbl,
                                               const float* __restrict__ A_log,
                                               const float* __restrict__ D_skip,
                                               const int* __restrict__ lengths,
                                               const float* __restrict__ hin) {
    __shared__ float2 sDU[TT][18];   // {delta, delta*u}
    __shared__ float2 sBC[TT][18];   // {B, C}
    __shared__ float  sY[TT][16];
    const int t = threadIdx.x;
    const int bid = blockIdx.x;
    const int s = bid & (SCH - 1);
    const int bd = bid >> 4;
    const int b = bd >> 7;
    const int d0 = (bd & 127) << 4;
    if (s * CH >= lengths[b]) return;    // fully masked chunk: y never consumed
    const int lr = t >> 2, lq = (t & 3) << 2;
    const int ch = t >> 4, n = t & 15;
    const int d = d0 + ch;
    const float Av2 = -__expf(A_log[d * NST + n]) * 1.44269504f;
    const float4 Dv4 = *(const float4*)(D_skip + d0 + lq);
    float h = hin[(size_t)bid * 256 + t];
    const size_t base = (size_t)b * LSEQ + (size_t)s * CH;

    for (int l0 = 0; l0 < CH; l0 += TT) {
        const size_t row = base + l0 + lr;
        float4 dv = *(const float4*)(dlt + row * DINNER + d0 + lq);
        ushort4 uv = *(const ushort4*)(uy + row * DINNER + d0 + lq);
        float4 zv = *(const float4*)(zb + row * DINNER + d0 + lq);
        float4 bv = *(const float4*)(xdbl + row * 96 + 64 + lq);
        float4 cv = *(const float4*)(xdbl + row * 96 + 80 + lq);
        const float uf0 = bf2f(uv.x), uf1 = bf2f(uv.y), uf2 = bf2f(uv.z), uf3 = bf2f(uv.w);
        float4 w0 = {dv.x, dv.x * uf0, dv.y, dv.y * uf1};
        float4 w1 = {dv.z, dv.z * uf2, dv.w, dv.w * uf3};
        *(float4*)&sDU[lr][lq]     = w0;
        *(float4*)&sDU[lr][lq + 2] = w1;
        float4 e0 = {bv.x, cv.x, bv.y, cv.y};
        float4 e1 = {bv.z, cv.z, bv.w, cv.w};
        *(float4*)&sBC[lr][lq]     = e0;
        *(float4*)&sBC[lr][lq + 2] = e1;
        __syncthreads();

#pragma unroll 16
        for (int r = 0; r < TT; ++r) {
            float2 ddu = sDU[r][ch];
            float2 bc  = sBC[r][n];
            float dA = __builtin_amdgcn_exp2f(ddu.x * Av2);
            h = fmaf(dA, h, ddu.y * bc.x);
            float p = h * bc.y;
            p += dpp_ror<0x128>(p);
            p += dpp_ror<0x124>(p);
            p += dpp_ror<0x122>(p);
            p += dpp_ror<0x121>(p);
            if (n == 0) sY[r][ch] = p;
        }
        __syncthreads();

        float4 yv = *(const float4*)&sY[lr][lq];
        ushort4 ov;
        ov.x = f2bf(fmaf(uf0, Dv4.x, yv.x) * siluf(zv.x));
        ov.y = f2bf(fmaf(uf1, Dv4.y, yv.y) * siluf(zv.y));
        ov.z = f2bf(fmaf(uf2, Dv4.z, yv.z) * siluf(zv.z));
        ov.w = f2bf(fmaf(uf3, Dv4.w, yv.w) * siluf(zv.w));
        *(ushort4*)(uy + row * DINNER + d0 + lq) = ov;
        __syncthreads();
    }
}

extern "C" void kernel_launch(void* const* d_in, const int* in_sizes, int n_in,
                              void* d_out, int out_size, void* d_ws, size_t ws_size,
                              hipStream_t stream) {
    const float* hs        = (const float*)d_in[0];
    const int*   lengths   = (const int*)d_in[1];
    const float* norm_w    = (const float*)d_in[2];
    const float* in_proj_w = (const float*)d_in[3];
    const float* conv_w    = (const float*)d_in[4];
    const float* x_proj_w  = (const float*)d_in[5];
    const float* dt_proj_w = (const float*)d_in[6];
    const float* dt_proj_b = (const float*)d_in[7];
    const float* A_log     = (const float*)d_in[8];
    const float* D_skip    = (const float*)d_in[9];
    const float* out_proj_w= (const float*)d_in[10];

    float* out = (float*)d_out;

    const int M = NB * LSEQ;                                            // 8192
    float* ur = (float*)d_ws;                                           // 8192x2048 f32 (64MB): u_raw -> dlt
    float* zb = ur + (size_t)M * DINNER;                                // 8192x2048 f32 (64MB): z
    unsigned short* u_bf = (unsigned short*)(zb + (size_t)M * DINNER);  // 8192x2048 bf16 (32MB): u -> y
    float* xdbl = (float*)(u_bf + (size_t)M * DINNER);                  // 8192x96 f32 (3MB)
    unsigned short* w_in  = (unsigned short*)(xdbl + (size_t)M * 96);   // 4096x1024 (8MB)
    unsigned short* w_out = w_in + (size_t)4096 * 1024;                 // 1024x2048 (4MB)
    unsigned short* w_x   = w_out + (size_t)1024 * 2048;                // 96x2048
    unsigned short* w_dt  = w_x + (size_t)96 * 2048;                    // 2048x64
    unsigned short* dtr   = w_dt + (size_t)2048 * 64;                   // 8192x64 bf16 (1MB)
    float* hin            = (float*)(dtr + (size_t)M * 64);             // 512*16*256 f32 (8MB)
    unsigned short* xn_bf = u_bf;          // alias: dead once conv overwrites it
    float* dlt  = ur;                      // alias: ur dead after conv
    float* hloc = (float*)w_in;            // alias: w_in dead after in_proj (8MB exact)
    float* sumd = (float*)dtr;             // alias: dtr dead after dt_proj

    // 1. fused RMSNorm->bf16 + fused weight conversions (1 launch)
    rmsnorm_cvt_k<<<M, 256, 0, stream>>>(hs, norm_w, xn_bf);
    cvt_all_k<<<6464, 256, 0, stream>>>(in_proj_w, out_proj_w, x_proj_w, dt_proj_w,
                                        w_in, w_out, w_x, w_dt);

    // 2. in_proj (bf16 MFMA, row-skip): split f32 stores ur | z  (8192x4096, K=1024)
    gemm_bf16<0><<<(4096 / 128) * (M / 128), 256, 0, stream>>>(
        xn_bf, DMODEL, w_in, DMODEL, ur, zb, DINNER, M, 4096, DMODEL, 4096 / 128,
        nullptr, nullptr, nullptr, lengths);

    // 3. causal depthwise conv + silu + mask -> u (bf16); masked blocks -> exact zeros
    conv_silu_k<<<NB * 512, 256, 0, stream>>>(ur, conv_w, lengths, u_bf);

    // 4. x_proj (bf16 MFMA, row-skip): B,C -> xdbl f32; dt_r -> dtr bf16 (fused)
    gemm_bf16<3><<<1 * (M / 128), 256, 0, stream>>>(
        u_bf, DINNER, w_x, DINNER, xdbl, nullptr, 96, M, 96, DINNER, 1,
        nullptr, nullptr, dtr, lengths);

    // 5. dt_proj (bf16 MFMA, row-skip) + softplus + mask -> delta f32 (over dead ur)
    gemm_bf16<1><<<(DINNER / 128) * (M / 128), 256, 0, stream>>>(
        dtr, 64, w_dt, 64, dlt, nullptr, DINNER, M, DINNER, 64, DINNER / 128,
        dt_proj_b, nullptr, nullptr, lengths);

    // 6. chunked selective scan (3 phases, chunk-skip); h_last -> tail of d_out
    {
        float* hlast = out + (size_t)M * DMODEL;
        const int nbd = NB * (DINNER / 16);                 // 512
        scan_p1<<<nbd * SCH, 256, 0, stream>>>(dlt, u_bf, xdbl, A_log, lengths, hloc, sumd);
        scan_p2<<<nbd, 256, 0, stream>>>(hloc, sumd, A_log, hin, hlast);
        scan_p3<<<nbd * SCH, 256, 0, stream>>>(dlt, zb, u_bf, xdbl, A_log, D_skip, lengths, hin);
    }

    // 7. out_proj (bf16 MFMA, row-skip -> residual copy) + residual + mask -> d_out
    gemm_bf16<2><<<(DMODEL / 128) * (M / 128), 256, 0, stream>>>(
        u_bf, DINNER, w_out, DINNER, out, nullptr, DMODEL, M, DMODEL, DINNER, DMODEL / 128,
        nullptr, hs, nullptr, lengths);
}

// Round 8
// 358.076 us; speedup vs baseline: 8.9650x; 1.3013x over previous
//
#include <hip/hip_runtime.h>
#include <cstdint>
#include <cstddef>

#define LSEQ 2048
#define NB   4
#define DMODEL 1024
#define DINNER 2048
#define NST  16
#define TT   64    // scan LDS time-tile
#define CH   128   // scan chunk length == GEMM tile height
#define SCH  (LSEQ / CH)   // 16 chunks
#define NBD  512           // NB * DINNER/16

typedef short bf16x8 __attribute__((ext_vector_type(8)));
typedef float f32x4  __attribute__((ext_vector_type(4)));

__device__ __forceinline__ float siluf(float x) { return x / (1.f + __expf(-x)); }

__device__ __forceinline__ unsigned short f2bf(float f) {
    unsigned u = __float_as_uint(f);
    u += 0x7FFF + ((u >> 16) & 1);     // round-to-nearest-even
    return (unsigned short)(u >> 16);
}
__device__ __forceinline__ float bf2f(unsigned short h) {
    return __uint_as_float(((unsigned)h) << 16);
}
__device__ __forceinline__ void gload_lds16(const void* g, void* l) {
    __builtin_amdgcn_global_load_lds(
        (const __attribute__((address_space(1))) unsigned int*)g,
        (__attribute__((address_space(3))) unsigned int*)l, 16, 0, 0);
}

template <int CTRL>
__device__ __forceinline__ float dpp_ror(float v) {
    return __int_as_float(__builtin_amdgcn_update_dpp(
        0, __float_as_int(v), CTRL, 0xf, 0xf, false));
}

// ---------------- fused RMSNorm + bf16 convert ----------------
__global__ __launch_bounds__(256) void rmsnorm_cvt_k(const float* __restrict__ x,
                                                     const float* __restrict__ nw,
                                                     unsigned short* __restrict__ o) {
    int row = blockIdx.x, t = threadIdx.x;
    float4 v = ((const float4*)(x + (size_t)row * DMODEL))[t];
    float s = v.x * v.x + v.y * v.y + v.z * v.z + v.w * v.w;
#pragma unroll
    for (int m = 32; m >= 1; m >>= 1) s += __shfl_xor(s, m);
    __shared__ float wsum[4];
    __shared__ float sinv;
    if ((t & 63) == 0) wsum[t >> 6] = s;
    __syncthreads();
    if (t == 0) {
        float tot = wsum[0] + wsum[1] + wsum[2] + wsum[3];
        sinv = rsqrtf(tot * (1.f / (float)DMODEL) + 1e-6f);
    }
    __syncthreads();
    float iv = sinv;
    float4 w = ((const float4*)nw)[t];
    ushort4 ov;
    ov.x = f2bf(v.x * iv * w.x); ov.y = f2bf(v.y * iv * w.y);
    ov.z = f2bf(v.z * iv * w.z); ov.w = f2bf(v.w * iv * w.w);
    ((ushort4*)(o + (size_t)row * DMODEL))[t] = ov;
}

// ---------------- fused weight conversions (4 matrices, 1 launch) ----------------
__global__ __launch_bounds__(256) void cvt_all_k(const float* __restrict__ s0, const float* __restrict__ s1,
                                                 const float* __restrict__ s2, const float* __restrict__ s3,
                                                 unsigned short* __restrict__ q0, unsigned short* __restrict__ q1,
                                                 unsigned short* __restrict__ q2, unsigned short* __restrict__ q3) {
    int i = blockIdx.x * 256 + threadIdx.x;
    const float* s; unsigned short* d; int off;
    if (i < 1048576)       { s = s0; d = q0; off = i; }
    else if (i < 1572864)  { s = s1; d = q1; off = i - 1048576; }
    else if (i < 1622016)  { s = s2; d = q2; off = i - 1572864; }
    else if (i < 1654784)  { s = s3; d = q3; off = i - 1622016; }
    else return;
    float4 v = ((const float4*)s)[off];
    ushort4 o;
    o.x = f2bf(v.x); o.y = f2bf(v.y); o.z = f2bf(v.z); o.w = f2bf(v.w);
    ((ushort4*)d)[off] = o;
}

// ---------------- bf16 MFMA NT GEMM with row-tile skip ----------------
// plain row-major block decode: bx = bid % nbx, by = bid / nbx.
// XCD = bid % 8 tracks bx (nbx % 8 == 0) or by (nbx == 1), so length-skip
// stays balanced across XCDs for any lengths.
// EPI 0: split f32 store: col<2048 -> Cv (ur), col>=2048 -> C2 (z)   (in_proj)
// EPI 1: softplus(acc+bias)*mask -> f32 store                        (dt_proj)
// EPI 2: residual + mask*acc -> f32; skipped tiles copy residual     (out_proj)
// EPI 3: col<64 -> bf16 aux (dtr); 64<=col<96 -> f32 Cv (xdbl, ld96) (x_proj)
template <int EPI>
__global__ __launch_bounds__(256) void gemm_bf16(
    const unsigned short* __restrict__ A, int lda,
    const unsigned short* __restrict__ W, int ldw,
    void* __restrict__ Cv, float* __restrict__ C2, int ldc,
    int M, int N, int K, int nbx,
    const float* __restrict__ bias,
    const float* __restrict__ residual,
    unsigned short* __restrict__ aux,
    const int* __restrict__ lengths) {
    __shared__ __align__(16) unsigned short As[128 * 64];
    __shared__ __align__(16) unsigned short Bs[128 * 64];
    const int bid = blockIdx.x;
    const int bx = bid % nbx, by = bid / nbx;
    const int row0 = by * 128, col0 = bx * 128;
    const int t = threadIdx.x;

    // row-tile skip: rows [row0,row0+128) all masked -> outputs never consumed
    const int len0 = lengths[row0 >> 11];
    if ((row0 & (LSEQ - 1)) >= len0) {
        if (EPI == 2) {
            float* C = (float*)Cv;
#pragma unroll
            for (int i = 0; i < 16; ++i) {
                int lin = i * 256 + t;                  // 4096 float4 = 128x128
                int r = lin >> 5, c = (lin & 31) << 2;
                *(float4*)(C + (size_t)(row0 + r) * ldc + col0 + c) =
                    *(const float4*)(residual + (size_t)(row0 + r) * ldc + col0 + c);
            }
        }
        return;
    }

    const int lane = t & 63;
    const int w = t >> 6;
    const int wr = w >> 1, wc = w & 1;

    f32x4 acc[4][4];
#pragma unroll
    for (int m = 0; m < 4; ++m)
#pragma unroll
        for (int n = 0; n < 4; ++n) acc[m][n] = f32x4{0.f, 0.f, 0.f, 0.f};

    const int rA = lane & 15;
    const int kH = (lane >> 4) << 3;

    for (int k0 = 0; k0 < K; k0 += 64) {
#pragma unroll
        for (int it = 0; it < 4; ++it) {
            int c = it * 256 + t;
            int r = c >> 3, cc = (c & 7) << 3;
            gload_lds16(A + (size_t)(row0 + r) * lda + k0 + cc, &As[c << 3]);
            int wrow = col0 + r; if (wrow >= N) wrow = N - 1;   // clamp (x_proj N=96)
            gload_lds16(W + (size_t)wrow * ldw + k0 + cc, &Bs[c << 3]);
        }
        __syncthreads();
#pragma unroll
        for (int ks = 0; ks < 2; ++ks) {
            const int kk = ks * 32 + kH;
            bf16x8 af[4], bfr[4];
#pragma unroll
            for (int m = 0; m < 4; ++m)
                af[m] = *(const bf16x8*)&As[(wr * 64 + m * 16 + rA) * 64 + kk];
#pragma unroll
            for (int n = 0; n < 4; ++n)
                bfr[n] = *(const bf16x8*)&Bs[(wc * 64 + n * 16 + rA) * 64 + kk];
#pragma unroll
            for (int m = 0; m < 4; ++m)
#pragma unroll
                for (int n = 0; n < 4; ++n)
                    acc[m][n] = __builtin_amdgcn_mfma_f32_16x16x32_bf16(
                        af[m], bfr[n], acc[m][n], 0, 0, 0);
        }
        __syncthreads();
    }
    const int cl = lane & 15, rg = lane >> 4;
#pragma unroll
    for (int m = 0; m < 4; ++m) {
#pragma unroll
        for (int j = 0; j < 4; ++j) {
            const int row = row0 + wr * 64 + m * 16 + rg * 4 + j;
            float msk = 1.f;
            if (EPI == 1 || EPI == 2) {
                msk = ((row & (LSEQ - 1)) < len0) ? 1.f : 0.f;
            }
#pragma unroll
            for (int n = 0; n < 4; ++n) {
                const int col = col0 + wc * 64 + n * 16 + cl;
                float v = acc[m][n][j];
                if (EPI == 0) {
                    if (col < DINNER) ((float*)Cv)[(size_t)row * DINNER + col] = v;
                    else              C2[(size_t)row * DINNER + col - DINNER] = v;
                } else if (EPI == 1) {
                    v += bias[col];
                    v = (v > 20.f) ? v : log1pf(__expf(v));
                    ((float*)Cv)[(size_t)row * ldc + col] = v * msk;
                } else if (EPI == 2) {
                    ((float*)Cv)[(size_t)row * ldc + col] =
                        residual[(size_t)row * ldc + col] + msk * v;
                } else {  // EPI 3
                    if (col < 64) aux[(size_t)row * 64 + col] = f2bf(v);
                    else if (col < 96) ((float*)Cv)[(size_t)row * 96 + col] = v;
                }
            }
        }
    }
}

// ---------------- causal depthwise conv (K=4) + SiLU + mask -> bf16 ----------------
// fully-masked blocks write exact zeros (no loads) so u == 0 at all masked rows
__global__ __launch_bounds__(256) void conv_silu_k(const float* __restrict__ ur,
                                                   const float* __restrict__ cw,
                                                   const int* __restrict__ lengths,
                                                   unsigned short* __restrict__ u) {
    const int g = blockIdx.x;              // NB * 512
    const int b = g >> 9;
    const int rem = g & 511;
    const int l0 = (rem >> 1) << 3;
    const int d4 = (rem & 1) * 1024 + threadIdx.x * 4;
    const int len = lengths[b];
    const size_t rb = (size_t)b * LSEQ;
    if (l0 >= len) {
        ushort4 z4 = {0, 0, 0, 0};
#pragma unroll
        for (int i = 0; i < 8; ++i)
            *(ushort4*)(u + (rb + l0 + i) * DINNER + d4) = z4;
        return;
    }
    float4 wq[4];
#pragma unroll
    for (int c = 0; c < 4; ++c) wq[c] = *(const float4*)(cw + 4 * (d4 + c));
    const float4 zero4 = {0.f, 0.f, 0.f, 0.f};
    float4 xm3 = (l0 - 3 >= 0 && l0 - 3 < len) ? *(const float4*)(ur + (rb + l0 - 3) * DINNER + d4) : zero4;
    float4 xm2 = (l0 - 2 >= 0 && l0 - 2 < len) ? *(const float4*)(ur + (rb + l0 - 2) * DINNER + d4) : zero4;
    float4 xm1 = (l0 - 1 >= 0 && l0 - 1 < len) ? *(const float4*)(ur + (rb + l0 - 1) * DINNER + d4) : zero4;
#pragma unroll
    for (int i = 0; i < 8; ++i) {
        const int l = l0 + i;
        const bool act = l < len;
        float4 x0 = act ? *(const float4*)(ur + (rb + l) * DINNER + d4) : zero4;
        float a0 = wq[0].x * xm3.x + wq[0].y * xm2.x + wq[0].z * xm1.x + wq[0].w * x0.x;
        float a1 = wq[1].x * xm3.y + wq[1].y * xm2.y + wq[1].z * xm1.y + wq[1].w * x0.y;
        float a2 = wq[2].x * xm3.z + wq[2].y * xm2.z + wq[2].z * xm1.z + wq[2].w * x0.z;
        float a3 = wq[3].x * xm3.w + wq[3].y * xm2.w + wq[3].z * xm1.w + wq[3].w * x0.w;
        ushort4 ov;
        ov.x = f2bf(act ? siluf(a0) : 0.f);
        ov.y = f2bf(act ? siluf(a1) : 0.f);
        ov.z = f2bf(act ? siluf(a2) : 0.f);
        ov.w = f2bf(act ? siluf(a3) : 0.f);
        *(ushort4*)(u + (rb + l) * DINNER + d4) = ov;
        xm3 = xm2; xm2 = xm1; xm1 = x0;
    }
}

// ---------------- scan phase 1: per-chunk local scan (h_in = 0) ----------------
// grid = SCH * NBD; s = bid >> 9 (so XCD = bd % 8 -> balanced under length-skip)
__global__ __launch_bounds__(256) void scan_p1(const float* __restrict__ dlt,
                                               const unsigned short* __restrict__ uy,
                                               const float* __restrict__ xdbl,
                                               const float* __restrict__ A_log,
                                               const int* __restrict__ lengths,
                                               float* __restrict__ hloc,
                                               float* __restrict__ sumd) {
    __shared__ float2 sDU[TT][18];   // {delta, delta*u}; padded stride
    __shared__ float  sB[TT][20];
    const int t = threadIdx.x;
    const int s = blockIdx.x >> 9;
    const int bd = blockIdx.x & (NBD - 1);
    const int b = bd >> 7;
    const int d0 = (bd & 127) << 4;
    const int n = t & 15, ch = t >> 4;
    const size_t hidx = ((size_t)bd * SCH + s) * 256 + t;
    if (s * CH >= lengths[b]) {          // fully masked chunk: exact identity
        hloc[hidx] = 0.f;
        if (n == 0) sumd[(bd * SCH + s) * 16 + ch] = 0.f;
        return;
    }
    const int lr = t >> 2, lq = (t & 3) << 2;
    const int d = d0 + ch;
    const float Av2 = -__expf(A_log[d * NST + n]) * 1.44269504f;
    float h = 0.f, sd = 0.f;
    const size_t base = (size_t)b * LSEQ + (size_t)s * CH;

    for (int l0 = 0; l0 < CH; l0 += TT) {
        const size_t row = base + l0 + lr;
        float4 dv = *(const float4*)(dlt + row * DINNER + d0 + lq);
        ushort4 uv = *(const ushort4*)(uy + row * DINNER + d0 + lq);
        float4 bv = *(const float4*)(xdbl + row * 96 + 64 + lq);
        float4 w0 = {dv.x, dv.x * bf2f(uv.x), dv.y, dv.y * bf2f(uv.y)};
        float4 w1 = {dv.z, dv.z * bf2f(uv.z), dv.w, dv.w * bf2f(uv.w)};
        *(float4*)&sDU[lr][lq]     = w0;
        *(float4*)&sDU[lr][lq + 2] = w1;
        *(float4*)&sB[lr][lq] = bv;
        __syncthreads();
#pragma unroll 16
        for (int r = 0; r < TT; ++r) {
            float2 ddu = sDU[r][ch];
            float Bn = sB[r][n];
            float dA = __builtin_amdgcn_exp2f(ddu.x * Av2);
            h = fmaf(dA, h, ddu.y * Bn);
            sd += ddu.x;
        }
        __syncthreads();
    }
    hloc[hidx] = h;
    if (n == 0) sumd[(bd * SCH + s) * 16 + ch] = sd;
}

// ---------------- scan phase 2: sequential chunk fix-up + h_last ----------------
__global__ __launch_bounds__(256) void scan_p2(const float* __restrict__ hloc,
                                               const float* __restrict__ sumd,
                                               const float* __restrict__ A_log,
                                               float* __restrict__ hin,
                                               float* __restrict__ out_h) {
    const int t = threadIdx.x;
    const int bd = blockIdx.x;
    const int b = bd >> 7;
    const int d = ((bd & 127) << 4) + (t >> 4);
    const int n = t & 15;
    const float Av2 = -__expf(A_log[d * NST + n]) * 1.44269504f;
    float h = 0.f;
#pragma unroll
    for (int s = 0; s < SCH; ++s) {
        const size_t idx = ((size_t)bd * SCH + s) * 256 + t;
        hin[idx] = h;
        float P = __builtin_amdgcn_exp2f(Av2 * sumd[(bd * SCH + s) * 16 + (t >> 4)]);
        h = fmaf(P, h, hloc[idx]);
    }
    out_h[((size_t)(b * DINNER + d)) * NST + n] = h;
}

// ---------------- scan phase 3: replay chunk from h_in, produce gated y ----------------
__global__ __launch_bounds__(256) void scan_p3(const float* __restrict__ dlt,
                                               const float* __restrict__ zb,
                                               unsigned short* uy,
                                               const float* __restrict__ xdbl,
                                               const float* __restrict__ A_log,
                                               const float* __restrict__ D_skip,
                                               const int* __restrict__ lengths,
                                               const float* __restrict__ hin) {
    __shared__ float2 sDU[TT][18];   // {delta, delta*u}
    __shared__ float2 sBC[TT][18];   // {B, C}
    __shared__ float  sY[TT][16];
    const int t = threadIdx.x;
    const int s = blockIdx.x >> 9;
    const int bd = blockIdx.x & (NBD - 1);
    const int b = bd >> 7;
    const int d0 = (bd & 127) << 4;
    if (s * CH >= lengths[b]) return;    // fully masked chunk: y never consumed
    const int lr = t >> 2, lq = (t & 3) << 2;
    const int ch = t >> 4, n = t & 15;
    const int d = d0 + ch;
    const float Av2 = -__expf(A_log[d * NST + n]) * 1.44269504f;
    const float4 Dv4 = *(const float4*)(D_skip + d0 + lq);
    float h = hin[((size_t)bd * SCH + s) * 256 + t];
    const size_t base = (size_t)b * LSEQ + (size_t)s * CH;

    for (int l0 = 0; l0 < CH; l0 += TT) {
        const size_t row = base + l0 + lr;
        float4 dv = *(const float4*)(dlt + row * DINNER + d0 + lq);
        ushort4 uv = *(const ushort4*)(uy + row * DINNER + d0 + lq);
        float4 zv = *(const float4*)(zb + row * DINNER + d0 + lq);
        float4 bv = *(const float4*)(xdbl + row * 96 + 64 + lq);
        float4 cv = *(const float4*)(xdbl + row * 96 + 80 + lq);
        const float uf0 = bf2f(uv.x), uf1 = bf2f(uv.y), uf2 = bf2f(uv.z), uf3 = bf2f(uv.w);
        float4 w0 = {dv.x, dv.x * uf0, dv.y, dv.y * uf1};
        float4 w1 = {dv.z, dv.z * uf2, dv.w, dv.w * uf3};
        *(float4*)&sDU[lr][lq]     = w0;
        *(float4*)&sDU[lr][lq + 2] = w1;
        float4 e0 = {bv.x, cv.x, bv.y, cv.y};
        float4 e1 = {bv.z, cv.z, bv.w, cv.w};
        *(float4*)&sBC[lr][lq]     = e0;
        *(float4*)&sBC[lr][lq + 2] = e1;
        __syncthreads();

#pragma unroll 16
        for (int r = 0; r < TT; ++r) {
            float2 ddu = sDU[r][ch];
            float2 bc  = sBC[r][n];
            float dA = __builtin_amdgcn_exp2f(ddu.x * Av2);
            h = fmaf(dA, h, ddu.y * bc.x);
            float p = h * bc.y;
            p += dpp_ror<0x128>(p);
            p += dpp_ror<0x124>(p);
            p += dpp_ror<0x122>(p);
            p += dpp_ror<0x121>(p);
            if (n == 0) sY[r][ch] = p;
        }
        __syncthreads();

        float4 yv = *(const float4*)&sY[lr][lq];
        ushort4 ov;
        ov.x = f2bf(fmaf(uf0, Dv4.x, yv.x) * siluf(zv.x));
        ov.y = f2bf(fmaf(uf1, Dv4.y, yv.y) * siluf(zv.y));
        ov.z = f2bf(fmaf(uf2, Dv4.z, yv.z) * siluf(zv.z));
        ov.w = f2bf(fmaf(uf3, Dv4.w, yv.w) * siluf(zv.w));
        *(ushort4*)(uy + row * DINNER + d0 + lq) = ov;
        __syncthreads();
    }
}

extern "C" void kernel_launch(void* const* d_in, const int* in_sizes, int n_in,
                              void* d_out, int out_size, void* d_ws, size_t ws_size,
                              hipStream_t stream) {
    const float* hs        = (const float*)d_in[0];
    const int*   lengths   = (const int*)d_in[1];
    const float* norm_w    = (const float*)d_in[2];
    const float* in_proj_w = (const float*)d_in[3];
    const float* conv_w    = (const float*)d_in[4];
    const float* x_proj_w  = (const float*)d_in[5];
    const float* dt_proj_w = (const float*)d_in[6];
    const float* dt_proj_b = (const float*)d_in[7];
    const float* A_log     = (const float*)d_in[8];
    const float* D_skip    = (const float*)d_in[9];
    const float* out_proj_w= (const float*)d_in[10];

    float* out = (float*)d_out;

    const int M = NB * LSEQ;                                            // 8192
    float* ur = (float*)d_ws;                                           // 8192x2048 f32 (64MB): u_raw -> dlt
    float* zb = ur + (size_t)M * DINNER;                                // 8192x2048 f32 (64MB): z
    unsigned short* u_bf = (unsigned short*)(zb + (size_t)M * DINNER);  // 8192x2048 bf16 (32MB): u -> y
    float* xdbl = (float*)(u_bf + (size_t)M * DINNER);                  // 8192x96 f32 (3MB)
    unsigned short* w_in  = (unsigned short*)(xdbl + (size_t)M * 96);   // 4096x1024 (8MB)
    unsigned short* w_out = w_in + (size_t)4096 * 1024;                 // 1024x2048 (4MB)
    unsigned short* w_x   = w_out + (size_t)1024 * 2048;                // 96x2048
    unsigned short* w_dt  = w_x + (size_t)96 * 2048;                    // 2048x64
    unsigned short* dtr   = w_dt + (size_t)2048 * 64;                   // 8192x64 bf16 (1MB)
    float* hin            = (float*)(dtr + (size_t)M * 64);             // 512*16*256 f32 (8MB)
    unsigned short* xn_bf = u_bf;          // alias: dead once conv overwrites it
    float* dlt  = ur;                      // alias: ur dead after conv
    float* hloc = (float*)w_in;            // alias: w_in dead after in_proj (8MB exact)
    float* sumd = (float*)dtr;             // alias: dtr dead after dt_proj

    // 1. fused RMSNorm->bf16 + fused weight conversions (1 launch)
    rmsnorm_cvt_k<<<M, 256, 0, stream>>>(hs, norm_w, xn_bf);
    cvt_all_k<<<6464, 256, 0, stream>>>(in_proj_w, out_proj_w, x_proj_w, dt_proj_w,
                                        w_in, w_out, w_x, w_dt);

    // 2. in_proj (bf16 MFMA, row-skip): split f32 stores ur | z  (8192x4096, K=1024)
    gemm_bf16<0><<<(4096 / 128) * (M / 128), 256, 0, stream>>>(
        xn_bf, DMODEL, w_in, DMODEL, ur, zb, DINNER, M, 4096, DMODEL, 4096 / 128,
        nullptr, nullptr, nullptr, lengths);

    // 3. causal depthwise conv + silu + mask -> u (bf16); masked blocks -> exact zeros
    conv_silu_k<<<NB * 512, 256, 0, stream>>>(ur, conv_w, lengths, u_bf);

    // 4. x_proj (bf16 MFMA, row-skip): B,C -> xdbl f32; dt_r -> dtr bf16 (fused)
    gemm_bf16<3><<<1 * (M / 128), 256, 0, stream>>>(
        u_bf, DINNER, w_x, DINNER, xdbl, nullptr, 96, M, 96, DINNER, 1,
        nullptr, nullptr, dtr, lengths);

    // 5. dt_proj (bf16 MFMA, row-skip) + softplus + mask -> delta f32 (over dead ur)
    gemm_bf16<1><<<(DINNER / 128) * (M / 128), 256, 0, stream>>>(
        dtr, 64, w_dt, 64, dlt, nullptr, DINNER, M, DINNER, 64, DINNER / 128,
        dt_proj_b, nullptr, nullptr, lengths);

    // 6. chunked selective scan (3 phases, chunk-skip); h_last -> tail of d_out
    {
        float* hlast = out + (size_t)M * DMODEL;
        scan_p1<<<NBD * SCH, 256, 0, stream>>>(dlt, u_bf, xdbl, A_log, lengths, hloc, sumd);
        scan_p2<<<NBD, 256, 0, stream>>>(hloc, sumd, A_log, hin, hlast);
        scan_p3<<<NBD * SCH, 256, 0, stream>>>(dlt, zb, u_bf, xdbl, A_log, D_skip, lengths, hin);
    }

    // 7. out_proj (bf16 MFMA, row-skip -> residual copy) + residual + mask -> d_out
    gemm_bf16<2><<<(DMODEL / 128) * (M / 128), 256, 0, stream>>>(
        u_bf, DINNER, w_out, DINNER, out, nullptr, DMODEL, M, DMODEL, DINNER, DMODEL / 128,
        nullptr, hs, nullptr, lengths);
}

// Round 9
// 357.875 us; speedup vs baseline: 8.9700x; 1.0006x over previous
//
#include <hip/hip_runtime.h>
#include <cstdint>
#include <cstddef>

#define LSEQ 2048
#define NB   4
#define DMODEL 1024
#define DINNER 2048
#define NST  16
#define TT   64    // scan LDS time-tile
#define CH   128   // scan chunk length == GEMM tile height
#define SCH  (LSEQ / CH)   // 16 chunks
#define NBD  512           // NB * DINNER/16

typedef short bf16x8 __attribute__((ext_vector_type(8)));
typedef float f32x4  __attribute__((ext_vector_type(4)));

__device__ __forceinline__ float siluf(float x) { return x / (1.f + __expf(-x)); }

__device__ __forceinline__ unsigned short f2bf(float f) {
    unsigned u = __float_as_uint(f);
    u += 0x7FFF + ((u >> 16) & 1);     // round-to-nearest-even
    return (unsigned short)(u >> 16);
}
__device__ __forceinline__ float bf2f(unsigned short h) {
    return __uint_as_float(((unsigned)h) << 16);
}
__device__ __forceinline__ void gload_lds16(const void* g, void* l) {
    __builtin_amdgcn_global_load_lds(
        (const __attribute__((address_space(1))) unsigned int*)g,
        (__attribute__((address_space(3))) unsigned int*)l, 16, 0, 0);
}

template <int CTRL>
__device__ __forceinline__ float dpp_ror(float v) {
    return __int_as_float(__builtin_amdgcn_update_dpp(
        0, __float_as_int(v), CTRL, 0xf, 0xf, false));
}

// ---------------- fused RMSNorm + bf16 convert ----------------
__global__ __launch_bounds__(256) void rmsnorm_cvt_k(const float* __restrict__ x,
                                                     const float* __restrict__ nw,
                                                     unsigned short* __restrict__ o) {
    int row = blockIdx.x, t = threadIdx.x;
    float4 v = ((const float4*)(x + (size_t)row * DMODEL))[t];
    float s = v.x * v.x + v.y * v.y + v.z * v.z + v.w * v.w;
#pragma unroll
    for (int m = 32; m >= 1; m >>= 1) s += __shfl_xor(s, m);
    __shared__ float wsum[4];
    __shared__ float sinv;
    if ((t & 63) == 0) wsum[t >> 6] = s;
    __syncthreads();
    if (t == 0) {
        float tot = wsum[0] + wsum[1] + wsum[2] + wsum[3];
        sinv = rsqrtf(tot * (1.f / (float)DMODEL) + 1e-6f);
    }
    __syncthreads();
    float iv = sinv;
    float4 w = ((const float4*)nw)[t];
    ushort4 ov;
    ov.x = f2bf(v.x * iv * w.x); ov.y = f2bf(v.y * iv * w.y);
    ov.z = f2bf(v.z * iv * w.z); ov.w = f2bf(v.w * iv * w.w);
    ((ushort4*)(o + (size_t)row * DMODEL))[t] = ov;
}

// ---------------- fused weight conversions (4 matrices, 1 launch) ----------------
__global__ __launch_bounds__(256) void cvt_all_k(const float* __restrict__ s0, const float* __restrict__ s1,
                                                 const float* __restrict__ s2, const float* __restrict__ s3,
                                                 unsigned short* __restrict__ q0, unsigned short* __restrict__ q1,
                                                 unsigned short* __restrict__ q2, unsigned short* __restrict__ q3) {
    int i = blockIdx.x * 256 + threadIdx.x;
    const float* s; unsigned short* d; int off;
    if (i < 1048576)       { s = s0; d = q0; off = i; }
    else if (i < 1572864)  { s = s1; d = q1; off = i - 1048576; }
    else if (i < 1622016)  { s = s2; d = q2; off = i - 1572864; }
    else if (i < 1654784)  { s = s3; d = q3; off = i - 1622016; }
    else return;
    float4 v = ((const float4*)s)[off];
    ushort4 o;
    o.x = f2bf(v.x); o.y = f2bf(v.y); o.z = f2bf(v.z); o.w = f2bf(v.w);
    ((ushort4*)d)[off] = o;
}

// ---------------- bf16 MFMA NT GEMM: double-buffered LDS, counted vmcnt ----------------
// plain row-major decode (XCD-balanced under length-skip; see round-8 note).
// EPI 0: split store: col<2048 -> f32 Cv (ur), col>=2048 -> bf16 C2 (z)  (in_proj)
// EPI 1: softplus(acc+bias)*mask -> f32 store                            (dt_proj)
// EPI 2: residual + mask*acc -> f32; skipped tiles copy residual         (out_proj)
// EPI 3: col<64 -> bf16 aux (dtr); 64<=col<96 -> f32 Cv (xdbl, ld96)     (x_proj)
template <int EPI>
__global__ __launch_bounds__(256) void gemm_bf16(
    const unsigned short* __restrict__ A, int lda,
    const unsigned short* __restrict__ W, int ldw,
    void* __restrict__ Cv, void* __restrict__ C2v, int ldc,
    int M, int N, int K, int nbx,
    const float* __restrict__ bias,
    const float* __restrict__ residual,
    unsigned short* __restrict__ aux,
    const int* __restrict__ lengths) {
    __shared__ __align__(16) unsigned short As[2][128 * 64];
    __shared__ __align__(16) unsigned short Bs[2][128 * 64];
    const int bid = blockIdx.x;
    const int bx = bid % nbx, by = bid / nbx;
    const int row0 = by * 128, col0 = bx * 128;
    const int t = threadIdx.x;

    // row-tile skip: rows [row0,row0+128) all masked -> outputs never consumed
    const int len0 = lengths[row0 >> 11];
    if ((row0 & (LSEQ - 1)) >= len0) {
        if (EPI == 2) {
            float* C = (float*)Cv;
#pragma unroll
            for (int i = 0; i < 16; ++i) {
                int lin = i * 256 + t;                  // 4096 float4 = 128x128
                int r = lin >> 5, c = (lin & 31) << 2;
                *(float4*)(C + (size_t)(row0 + r) * ldc + col0 + c) =
                    *(const float4*)(residual + (size_t)(row0 + r) * ldc + col0 + c);
            }
        }
        return;
    }

    const int lane = t & 63;
    const int w = t >> 6;
    const int wr = w >> 1, wc = w & 1;

    f32x4 acc[4][4];
#pragma unroll
    for (int m = 0; m < 4; ++m)
#pragma unroll
        for (int n = 0; n < 4; ++n) acc[m][n] = f32x4{0.f, 0.f, 0.f, 0.f};

    const int rA = lane & 15;
    const int kH = (lane >> 4) << 3;
    const int NT = K >> 6;

    // stage one 128x64 K-tile pair into buffer `sel`
    auto STAGE = [&](int sel, int k0) {
#pragma unroll
        for (int it = 0; it < 4; ++it) {
            int c = it * 256 + t;
            int r = c >> 3, cc = (c & 7) << 3;
            gload_lds16(A + (size_t)(row0 + r) * lda + k0 + cc, &As[sel][c << 3]);
            int wrow = col0 + r; if (wrow >= N) wrow = N - 1;   // clamp (x_proj N=96)
            gload_lds16(W + (size_t)wrow * ldw + k0 + cc, &Bs[sel][c << 3]);
        }
    };

    STAGE(0, 0);
    for (int kt = 0; kt < NT; ++kt) {
        const int cur = kt & 1;
        if (kt + 1 < NT) STAGE(cur ^ 1, (kt + 1) << 6);
        __builtin_amdgcn_sched_barrier(0);
        if (kt + 1 < NT) { asm volatile("s_waitcnt vmcnt(8)" ::: "memory"); }
        else             { asm volatile("s_waitcnt vmcnt(0)" ::: "memory"); }
        __builtin_amdgcn_sched_barrier(0);
        __builtin_amdgcn_s_barrier();
        __builtin_amdgcn_sched_barrier(0);
#pragma unroll
        for (int ks = 0; ks < 2; ++ks) {
            const int kk = ks * 32 + kH;
            bf16x8 af[4], bfr[4];
#pragma unroll
            for (int m = 0; m < 4; ++m)
                af[m] = *(const bf16x8*)&As[cur][(wr * 64 + m * 16 + rA) * 64 + kk];
#pragma unroll
            for (int n = 0; n < 4; ++n)
                bfr[n] = *(const bf16x8*)&Bs[cur][(wc * 64 + n * 16 + rA) * 64 + kk];
#pragma unroll
            for (int m = 0; m < 4; ++m)
#pragma unroll
                for (int n = 0; n < 4; ++n)
                    acc[m][n] = __builtin_amdgcn_mfma_f32_16x16x32_bf16(
                        af[m], bfr[n], acc[m][n], 0, 0, 0);
        }
        __builtin_amdgcn_sched_barrier(0);
        asm volatile("s_waitcnt lgkmcnt(0)" ::: "memory");
        __builtin_amdgcn_s_barrier();
        __builtin_amdgcn_sched_barrier(0);
    }

    const int cl = lane & 15, rg = lane >> 4;
#pragma unroll
    for (int m = 0; m < 4; ++m) {
#pragma unroll
        for (int j = 0; j < 4; ++j) {
            const int row = row0 + wr * 64 + m * 16 + rg * 4 + j;
            float msk = 1.f;
            if (EPI == 1 || EPI == 2) {
                msk = ((row & (LSEQ - 1)) < len0) ? 1.f : 0.f;
            }
#pragma unroll
            for (int n = 0; n < 4; ++n) {
                const int col = col0 + wc * 64 + n * 16 + cl;
                float v = acc[m][n][j];
                if (EPI == 0) {
                    if (col < DINNER) ((float*)Cv)[(size_t)row * DINNER + col] = v;
                    else ((unsigned short*)C2v)[(size_t)row * DINNER + col - DINNER] = f2bf(v);
                } else if (EPI == 1) {
                    v += bias[col];
                    v = (v > 20.f) ? v : log1pf(__expf(v));
                    ((float*)Cv)[(size_t)row * ldc + col] = v * msk;
                } else if (EPI == 2) {
                    ((float*)Cv)[(size_t)row * ldc + col] =
                        residual[(size_t)row * ldc + col] + msk * v;
                } else {  // EPI 3
                    if (col < 64) aux[(size_t)row * 64 + col] = f2bf(v);
                    else if (col < 96) ((float*)Cv)[(size_t)row * 96 + col] = v;
                }
            }
        }
    }
}

// ---------------- causal depthwise conv (K=4) + SiLU + mask -> bf16 ----------------
// fully-masked blocks write exact zeros (no loads) so u == 0 at all masked rows
__global__ __launch_bounds__(256) void conv_silu_k(const float* __restrict__ ur,
                                                   const float* __restrict__ cw,
                                                   const int* __restrict__ lengths,
                                                   unsigned short* __restrict__ u) {
    const int g = blockIdx.x;              // NB * 512
    const int b = g >> 9;
    const int rem = g & 511;
    const int l0 = (rem >> 1) << 3;
    const int d4 = (rem & 1) * 1024 + threadIdx.x * 4;
    const int len = lengths[b];
    const size_t rb = (size_t)b * LSEQ;
    if (l0 >= len) {
        ushort4 z4 = {0, 0, 0, 0};
#pragma unroll
        for (int i = 0; i < 8; ++i)
            *(ushort4*)(u + (rb + l0 + i) * DINNER + d4) = z4;
        return;
    }
    float4 wq[4];
#pragma unroll
    for (int c = 0; c < 4; ++c) wq[c] = *(const float4*)(cw + 4 * (d4 + c));
    const float4 zero4 = {0.f, 0.f, 0.f, 0.f};
    float4 xm3 = (l0 - 3 >= 0 && l0 - 3 < len) ? *(const float4*)(ur + (rb + l0 - 3) * DINNER + d4) : zero4;
    float4 xm2 = (l0 - 2 >= 0 && l0 - 2 < len) ? *(const float4*)(ur + (rb + l0 - 2) * DINNER + d4) : zero4;
    float4 xm1 = (l0 - 1 >= 0 && l0 - 1 < len) ? *(const float4*)(ur + (rb + l0 - 1) * DINNER + d4) : zero4;
#pragma unroll
    for (int i = 0; i < 8; ++i) {
        const int l = l0 + i;
        const bool act = l < len;
        float4 x0 = act ? *(const float4*)(ur + (rb + l) * DINNER + d4) : zero4;
        float a0 = wq[0].x * xm3.x + wq[0].y * xm2.x + wq[0].z * xm1.x + wq[0].w * x0.x;
        float a1 = wq[1].x * xm3.y + wq[1].y * xm2.y + wq[1].z * xm1.y + wq[1].w * x0.y;
        float a2 = wq[2].x * xm3.z + wq[2].y * xm2.z + wq[2].z * xm1.z + wq[2].w * x0.z;
        float a3 = wq[3].x * xm3.w + wq[3].y * xm2.w + wq[3].z * xm1.w + wq[3].w * x0.w;
        ushort4 ov;
        ov.x = f2bf(act ? siluf(a0) : 0.f);
        ov.y = f2bf(act ? siluf(a1) : 0.f);
        ov.z = f2bf(act ? siluf(a2) : 0.f);
        ov.w = f2bf(act ? siluf(a3) : 0.f);
        *(ushort4*)(u + (rb + l) * DINNER + d4) = ov;
        xm3 = xm2; xm2 = xm1; xm1 = x0;
    }
}

// ---------------- scan phase 1: per-chunk local scan (h_in = 0) ----------------
__global__ __launch_bounds__(256) void scan_p1(const float* __restrict__ dlt,
                                               const unsigned short* __restrict__ uy,
                                               const float* __restrict__ xdbl,
                                               const float* __restrict__ A_log,
                                               const int* __restrict__ lengths,
                                               float* __restrict__ hloc,
                                               float* __restrict__ sumd) {
    __shared__ float2 sDU[TT][18];   // {delta, delta*u}; padded stride
    __shared__ float  sB[TT][20];
    const int t = threadIdx.x;
    const int s = blockIdx.x >> 9;
    const int bd = blockIdx.x & (NBD - 1);
    const int b = bd >> 7;
    const int d0 = (bd & 127) << 4;
    const int n = t & 15, ch = t >> 4;
    const size_t hidx = ((size_t)bd * SCH + s) * 256 + t;
    if (s * CH >= lengths[b]) {          // fully masked chunk: exact identity
        hloc[hidx] = 0.f;
        if (n == 0) sumd[(bd * SCH + s) * 16 + ch] = 0.f;
        return;
    }
    const int lr = t >> 2, lq = (t & 3) << 2;
    const int d = d0 + ch;
    const float Av2 = -__expf(A_log[d * NST + n]) * 1.44269504f;
    float h = 0.f, sd = 0.f;
    const size_t base = (size_t)b * LSEQ + (size_t)s * CH;

    for (int l0 = 0; l0 < CH; l0 += TT) {
        const size_t row = base + l0 + lr;
        float4 dv = *(const float4*)(dlt + row * DINNER + d0 + lq);
        ushort4 uv = *(const ushort4*)(uy + row * DINNER + d0 + lq);
        float4 bv = *(const float4*)(xdbl + row * 96 + 64 + lq);
        float4 w0 = {dv.x, dv.x * bf2f(uv.x), dv.y, dv.y * bf2f(uv.y)};
        float4 w1 = {dv.z, dv.z * bf2f(uv.z), dv.w, dv.w * bf2f(uv.w)};
        *(float4*)&sDU[lr][lq]     = w0;
        *(float4*)&sDU[lr][lq + 2] = w1;
        *(float4*)&sB[lr][lq] = bv;
        __syncthreads();
#pragma unroll 16
        for (int r = 0; r < TT; ++r) {
            float2 ddu = sDU[r][ch];
            float Bn = sB[r][n];
            float dA = __builtin_amdgcn_exp2f(ddu.x * Av2);
            h = fmaf(dA, h, ddu.y * Bn);
            sd += ddu.x;
        }
        __syncthreads();
    }
    hloc[hidx] = h;
    if (n == 0) sumd[(bd * SCH + s) * 16 + ch] = sd;
}

// ---------------- scan phase 2: sequential chunk fix-up + h_last ----------------
__global__ __launch_bounds__(256) void scan_p2(const float* __restrict__ hloc,
                                               const float* __restrict__ sumd,
                                               const float* __restrict__ A_log,
                                               float* __restrict__ hin,
                                               float* __restrict__ out_h) {
    const int t = threadIdx.x;
    const int bd = blockIdx.x;
    const int b = bd >> 7;
    const int d = ((bd & 127) << 4) + (t >> 4);
    const int n = t & 15;
    const float Av2 = -__expf(A_log[d * NST + n]) * 1.44269504f;
    float h = 0.f;
#pragma unroll
    for (int s = 0; s < SCH; ++s) {
        const size_t idx = ((size_t)bd * SCH + s) * 256 + t;
        hin[idx] = h;
        float P = __builtin_amdgcn_exp2f(Av2 * sumd[(bd * SCH + s) * 16 + (t >> 4)]);
        h = fmaf(P, h, hloc[idx]);
    }
    out_h[((size_t)(b * DINNER + d)) * NST + n] = h;
}

// ---------------- scan phase 3: replay chunk from h_in, produce gated y ----------------
__global__ __launch_bounds__(256) void scan_p3(const float* __restrict__ dlt,
                                               const unsigned short* __restrict__ zb,  // bf16 z
                                               unsigned short* uy,
                                               const float* __restrict__ xdbl,
                                               const float* __restrict__ A_log,
                                               const float* __restrict__ D_skip,
                                               const int* __restrict__ lengths,
                                               const float* __restrict__ hin) {
    __shared__ float2 sDU[TT][18];   // {delta, delta*u}
    __shared__ float2 sBC[TT][18];   // {B, C}
    __shared__ float  sY[TT][16];
    const int t = threadIdx.x;
    const int s = blockIdx.x >> 9;
    const int bd = blockIdx.x & (NBD - 1);
    const int b = bd >> 7;
    const int d0 = (bd & 127) << 4;
    if (s * CH >= lengths[b]) return;    // fully masked chunk: y never consumed
    const int lr = t >> 2, lq = (t & 3) << 2;
    const int ch = t >> 4, n = t & 15;
    const int d = d0 + ch;
    const float Av2 = -__expf(A_log[d * NST + n]) * 1.44269504f;
    const float4 Dv4 = *(const float4*)(D_skip + d0 + lq);
    float h = hin[((size_t)bd * SCH + s) * 256 + t];
    const size_t base = (size_t)b * LSEQ + (size_t)s * CH;

    for (int l0 = 0; l0 < CH; l0 += TT) {
        const size_t row = base + l0 + lr;
        float4 dv = *(const float4*)(dlt + row * DINNER + d0 + lq);
        ushort4 uv = *(const ushort4*)(uy + row * DINNER + d0 + lq);
        ushort4 zu = *(const ushort4*)(zb + row * DINNER + d0 + lq);
        float4 bv = *(const float4*)(xdbl + row * 96 + 64 + lq);
        float4 cv = *(const float4*)(xdbl + row * 96 + 80 + lq);
        const float uf0 = bf2f(uv.x), uf1 = bf2f(uv.y), uf2 = bf2f(uv.z), uf3 = bf2f(uv.w);
        float4 w0 = {dv.x, dv.x * uf0, dv.y, dv.y * uf1};
        float4 w1 = {dv.z, dv.z * uf2, dv.w, dv.w * uf3};
        *(float4*)&sDU[lr][lq]     = w0;
        *(float4*)&sDU[lr][lq + 2] = w1;
        float4 e0 = {bv.x, cv.x, bv.y, cv.y};
        float4 e1 = {bv.z, cv.z, bv.w, cv.w};
        *(float4*)&sBC[lr][lq]     = e0;
        *(float4*)&sBC[lr][lq + 2] = e1;
        __syncthreads();

#pragma unroll 16
        for (int r = 0; r < TT; ++r) {
            float2 ddu = sDU[r][ch];
            float2 bc  = sBC[r][n];
            float dA = __builtin_amdgcn_exp2f(ddu.x * Av2);
            h = fmaf(dA, h, ddu.y * bc.x);
            float p = h * bc.y;
            p += dpp_ror<0x128>(p);
            p += dpp_ror<0x124>(p);
            p += dpp_ror<0x122>(p);
            p += dpp_ror<0x121>(p);
            if (n == 0) sY[r][ch] = p;
        }
        __syncthreads();

        float4 yv = *(const float4*)&sY[lr][lq];
        ushort4 ov;
        ov.x = f2bf(fmaf(uf0, Dv4.x, yv.x) * siluf(bf2f(zu.x)));
        ov.y = f2bf(fmaf(uf1, Dv4.y, yv.y) * siluf(bf2f(zu.y)));
        ov.z = f2bf(fmaf(uf2, Dv4.z, yv.z) * siluf(bf2f(zu.z)));
        ov.w = f2bf(fmaf(uf3, Dv4.w, yv.w) * siluf(bf2f(zu.w)));
        *(ushort4*)(uy + row * DINNER + d0 + lq) = ov;
        __syncthreads();
    }
}

extern "C" void kernel_launch(void* const* d_in, const int* in_sizes, int n_in,
                              void* d_out, int out_size, void* d_ws, size_t ws_size,
                              hipStream_t stream) {
    const float* hs        = (const float*)d_in[0];
    const int*   lengths   = (const int*)d_in[1];
    const float* norm_w    = (const float*)d_in[2];
    const float* in_proj_w = (const float*)d_in[3];
    const float* conv_w    = (const float*)d_in[4];
    const float* x_proj_w  = (const float*)d_in[5];
    const float* dt_proj_w = (const float*)d_in[6];
    const float* dt_proj_b = (const float*)d_in[7];
    const float* A_log     = (const float*)d_in[8];
    const float* D_skip    = (const float*)d_in[9];
    const float* out_proj_w= (const float*)d_in[10];

    float* out = (float*)d_out;

    const int M = NB * LSEQ;                                            // 8192
    float* ur = (float*)d_ws;                                           // 8192x2048 f32 (64MB): u_raw -> dlt
    unsigned short* zb = (unsigned short*)(ur + (size_t)M * DINNER);    // 8192x2048 bf16 (32MB): z
    unsigned short* u_bf = zb + (size_t)M * DINNER;                     // 8192x2048 bf16 (32MB): u -> y
    float* xdbl = (float*)(u_bf + (size_t)M * DINNER);                  // 8192x96 f32 (3MB)
    unsigned short* w_in  = (unsigned short*)(xdbl + (size_t)M * 96);   // 4096x1024 (8MB)
    unsigned short* w_out = w_in + (size_t)4096 * 1024;                 // 1024x2048 (4MB)
    unsigned short* w_x   = w_out + (size_t)1024 * 2048;                // 96x2048
    unsigned short* w_dt  = w_x + (size_t)96 * 2048;                    // 2048x64
    unsigned short* dtr   = w_dt + (size_t)2048 * 64;                   // 8192x64 bf16 (1MB)
    float* hin            = (float*)(dtr + (size_t)M * 64);             // 512*16*256 f32 (8MB)
    unsigned short* xn_bf = u_bf;          // alias: dead once conv overwrites it
    float* dlt  = ur;                      // alias: ur dead after conv
    float* hloc = (float*)w_in;            // alias: w_in dead after in_proj (8MB exact)
    float* sumd = (float*)dtr;             // alias: dtr dead after dt_proj

    // 1. fused RMSNorm->bf16 + fused weight conversions (1 launch)
    rmsnorm_cvt_k<<<M, 256, 0, stream>>>(hs, norm_w, xn_bf);
    cvt_all_k<<<6464, 256, 0, stream>>>(in_proj_w, out_proj_w, x_proj_w, dt_proj_w,
                                        w_in, w_out, w_x, w_dt);

    // 2. in_proj (bf16 MFMA dbuf, row-skip): ur f32 | z bf16  (8192x4096, K=1024)
    gemm_bf16<0><<<(4096 / 128) * (M / 128), 256, 0, stream>>>(
        xn_bf, DMODEL, w_in, DMODEL, ur, zb, DINNER, M, 4096, DMODEL, 4096 / 128,
        nullptr, nullptr, nullptr, lengths);

    // 3. causal depthwise conv + silu + mask -> u (bf16); masked blocks -> exact zeros
    conv_silu_k<<<NB * 512, 256, 0, stream>>>(ur, conv_w, lengths, u_bf);

    // 4. x_proj (bf16 MFMA dbuf, row-skip): B,C -> xdbl f32; dt_r -> dtr bf16 (fused)
    gemm_bf16<3><<<1 * (M / 128), 256, 0, stream>>>(
        u_bf, DINNER, w_x, DINNER, xdbl, nullptr, 96, M, 96, DINNER, 1,
        nullptr, nullptr, dtr, lengths);

    // 5. dt_proj (bf16 MFMA, row-skip) + softplus + mask -> delta f32 (over dead ur)
    gemm_bf16<1><<<(DINNER / 128) * (M / 128), 256, 0, stream>>>(
        dtr, 64, w_dt, 64, dlt, nullptr, DINNER, M, DINNER, 64, DINNER / 128,
        dt_proj_b, nullptr, nullptr, lengths);

    // 6. chunked selective scan (3 phases, chunk-skip); h_last -> tail of d_out
    {
        float* hlast = out + (size_t)M * DMODEL;
        scan_p1<<<NBD * SCH, 256, 0, stream>>>(dlt, u_bf, xdbl, A_log, lengths, hloc, sumd);
        scan_p2<<<NBD, 256, 0, stream>>>(hloc, sumd, A_log, hin, hlast);
        scan_p3<<<NBD * SCH, 256, 0, stream>>>(dlt, zb, u_bf, xdbl, A_log, D_skip, lengths, hin);
    }

    // 7. out_proj (bf16 MFMA dbuf, row-skip -> residual copy) + residual + mask -> d_out
    gemm_bf16<2><<<(DMODEL / 128) * (M / 128), 256, 0, stream>>>(
        u_bf, DINNER, w_out, DINNER, out, nullptr, DMODEL, M, DMODEL, DINNER, DMODEL / 128,
        nullptr, hs, nullptr, lengths);
}

// Round 10
// 326.652 us; speedup vs baseline: 9.8274x; 1.0956x over previous
//
#include <hip/hip_runtime.h>
#include <cstdint>
#include <cstddef>

#define LSEQ 2048
#define NB   4
#define DMODEL 1024
#define DINNER 2048
#define NST  16
#define TT   64    // scan LDS time-tile
#define CH   128   // scan chunk length == GEMM tile height
#define SCH  (LSEQ / CH)   // 16 chunks
#define NBD  512           // NB * DINNER/16

typedef short bf16x8 __attribute__((ext_vector_type(8)));
typedef float f32x4  __attribute__((ext_vector_type(4)));

__device__ __forceinline__ float siluf(float x) { return x / (1.f + __expf(-x)); }

__device__ __forceinline__ unsigned short f2bf(float f) {
    unsigned u = __float_as_uint(f);
    u += 0x7FFF + ((u >> 16) & 1);     // round-to-nearest-even
    return (unsigned short)(u >> 16);
}
__device__ __forceinline__ float bf2f(unsigned short h) {
    return __uint_as_float(((unsigned)h) << 16);
}
__device__ __forceinline__ void gload_lds16(const void* g, void* l) {
    __builtin_amdgcn_global_load_lds(
        (const __attribute__((address_space(1))) unsigned int*)g,
        (__attribute__((address_space(3))) unsigned int*)l, 16, 0, 0);
}

template <int CTRL>
__device__ __forceinline__ float dpp_ror(float v) {
    return __int_as_float(__builtin_amdgcn_update_dpp(
        0, __float_as_int(v), CTRL, 0xf, 0xf, false));
}

// ---------------- fused RMSNorm + bf16 convert ----------------
__global__ __launch_bounds__(256) void rmsnorm_cvt_k(const float* __restrict__ x,
                                                     const float* __restrict__ nw,
                                                     unsigned short* __restrict__ o) {
    int row = blockIdx.x, t = threadIdx.x;
    float4 v = ((const float4*)(x + (size_t)row * DMODEL))[t];
    float s = v.x * v.x + v.y * v.y + v.z * v.z + v.w * v.w;
#pragma unroll
    for (int m = 32; m >= 1; m >>= 1) s += __shfl_xor(s, m);
    __shared__ float wsum[4];
    __shared__ float sinv;
    if ((t & 63) == 0) wsum[t >> 6] = s;
    __syncthreads();
    if (t == 0) {
        float tot = wsum[0] + wsum[1] + wsum[2] + wsum[3];
        sinv = rsqrtf(tot * (1.f / (float)DMODEL) + 1e-6f);
    }
    __syncthreads();
    float iv = sinv;
    float4 w = ((const float4*)nw)[t];
    ushort4 ov;
    ov.x = f2bf(v.x * iv * w.x); ov.y = f2bf(v.y * iv * w.y);
    ov.z = f2bf(v.z * iv * w.z); ov.w = f2bf(v.w * iv * w.w);
    ((ushort4*)(o + (size_t)row * DMODEL))[t] = ov;
}

// ---------------- fused weight conversions (4 matrices, 1 launch) ----------------
__global__ __launch_bounds__(256) void cvt_all_k(const float* __restrict__ s0, const float* __restrict__ s1,
                                                 const float* __restrict__ s2, const float* __restrict__ s3,
                                                 unsigned short* __restrict__ q0, unsigned short* __restrict__ q1,
                                                 unsigned short* __restrict__ q2, unsigned short* __restrict__ q3) {
    int i = blockIdx.x * 256 + threadIdx.x;
    const float* s; unsigned short* d; int off;
    if (i < 1048576)       { s = s0; d = q0; off = i; }
    else if (i < 1572864)  { s = s1; d = q1; off = i - 1048576; }
    else if (i < 1622016)  { s = s2; d = q2; off = i - 1572864; }
    else if (i < 1654784)  { s = s3; d = q3; off = i - 1622016; }
    else return;
    float4 v = ((const float4*)s)[off];
    ushort4 o;
    o.x = f2bf(v.x); o.y = f2bf(v.y); o.z = f2bf(v.z); o.w = f2bf(v.w);
    ((ushort4*)d)[off] = o;
}

// ---------------- bf16 MFMA NT GEMM: dbuf LDS + counted vmcnt + XOR swizzle ----------------
// LDS chunk (r, cb) holds global chunk (r, cb ^ (r&7)); reads XOR kk with ((rA&7)<<3).
// Kills the 16-way bank conflict of the 128B-stride row-major tile (T2, m201 pattern).
// EPI 0: split store: col<2048 -> f32 Cv (ur), col>=2048 -> bf16 C2 (z)  (in_proj)
// EPI 1: softplus(acc+bias)*mask -> f32 store                            (dt_proj)
// EPI 2: residual + mask*acc -> f32; skipped tiles copy residual         (out_proj)
// EPI 3: col<64 -> bf16 aux (dtr); 64<=col<96 -> f32 Cv (xdbl, ld96)     (x_proj)
template <int EPI>
__global__ __launch_bounds__(256) void gemm_bf16(
    const unsigned short* __restrict__ A, int lda,
    const unsigned short* __restrict__ W, int ldw,
    void* __restrict__ Cv, void* __restrict__ C2v, int ldc,
    int M, int N, int K, int nbx,
    const float* __restrict__ bias,
    const float* __restrict__ residual,
    unsigned short* __restrict__ aux,
    const int* __restrict__ lengths) {
    __shared__ __align__(16) unsigned short As[2][128 * 64];
    __shared__ __align__(16) unsigned short Bs[2][128 * 64];
    const int bid = blockIdx.x;
    const int bx = bid % nbx, by = bid / nbx;
    const int row0 = by * 128, col0 = bx * 128;
    const int t = threadIdx.x;

    // row-tile skip: rows [row0,row0+128) all masked -> outputs never consumed
    const int len0 = lengths[row0 >> 11];
    if ((row0 & (LSEQ - 1)) >= len0) {
        if (EPI == 2) {
            float* C = (float*)Cv;
#pragma unroll
            for (int i = 0; i < 16; ++i) {
                int lin = i * 256 + t;                  // 4096 float4 = 128x128
                int r = lin >> 5, c = (lin & 31) << 2;
                *(float4*)(C + (size_t)(row0 + r) * ldc + col0 + c) =
                    *(const float4*)(residual + (size_t)(row0 + r) * ldc + col0 + c);
            }
        }
        return;
    }

    const int lane = t & 63;
    const int w = t >> 6;
    const int wr = w >> 1, wc = w & 1;

    f32x4 acc[4][4];
#pragma unroll
    for (int m = 0; m < 4; ++m)
#pragma unroll
        for (int n = 0; n < 4; ++n) acc[m][n] = f32x4{0.f, 0.f, 0.f, 0.f};

    const int rA = lane & 15;
    const int kH = (lane >> 4) << 3;
    const int NT = K >> 6;
    const int swzR = (rA & 7) << 3;      // read-side XOR (element units)

    // stage one 128x64 K-tile pair into buffer `sel`; source pre-swizzled
    auto STAGE = [&](int sel, int k0) {
#pragma unroll
        for (int it = 0; it < 4; ++it) {
            int c = it * 256 + t;
            int r = c >> 3;
            int cc = ((c & 7) ^ (r & 7)) << 3;           // pre-swizzled source chunk
            gload_lds16(A + (size_t)(row0 + r) * lda + k0 + cc, &As[sel][c << 3]);
            int wrow = col0 + r; if (wrow >= N) wrow = N - 1;   // clamp (x_proj N=96)
            gload_lds16(W + (size_t)wrow * ldw + k0 + cc, &Bs[sel][c << 3]);
        }
    };

    STAGE(0, 0);
    for (int kt = 0; kt < NT; ++kt) {
        const int cur = kt & 1;
        if (kt + 1 < NT) STAGE(cur ^ 1, (kt + 1) << 6);
        __builtin_amdgcn_sched_barrier(0);
        if (kt + 1 < NT) { asm volatile("s_waitcnt vmcnt(8)" ::: "memory"); }
        else             { asm volatile("s_waitcnt vmcnt(0)" ::: "memory"); }
        __builtin_amdgcn_sched_barrier(0);
        __builtin_amdgcn_s_barrier();
        __builtin_amdgcn_sched_barrier(0);
#pragma unroll
        for (int ks = 0; ks < 2; ++ks) {
            const int kkS = (ks * 32 + kH) ^ swzR;       // swizzled read offset
            bf16x8 af[4], bfr[4];
#pragma unroll
            for (int m = 0; m < 4; ++m)
                af[m] = *(const bf16x8*)&As[cur][(wr * 64 + m * 16 + rA) * 64 + kkS];
#pragma unroll
            for (int n = 0; n < 4; ++n)
                bfr[n] = *(const bf16x8*)&Bs[cur][(wc * 64 + n * 16 + rA) * 64 + kkS];
#pragma unroll
            for (int m = 0; m < 4; ++m)
#pragma unroll
                for (int n = 0; n < 4; ++n)
                    acc[m][n] = __builtin_amdgcn_mfma_f32_16x16x32_bf16(
                        af[m], bfr[n], acc[m][n], 0, 0, 0);
        }
        __builtin_amdgcn_sched_barrier(0);
        asm volatile("s_waitcnt lgkmcnt(0)" ::: "memory");
        __builtin_amdgcn_s_barrier();
        __builtin_amdgcn_sched_barrier(0);
    }

    const int cl = lane & 15, rg = lane >> 4;
#pragma unroll
    for (int m = 0; m < 4; ++m) {
#pragma unroll
        for (int j = 0; j < 4; ++j) {
            const int row = row0 + wr * 64 + m * 16 + rg * 4 + j;
            float msk = 1.f;
            if (EPI == 1 || EPI == 2) {
                msk = ((row & (LSEQ - 1)) < len0) ? 1.f : 0.f;
            }
#pragma unroll
            for (int n = 0; n < 4; ++n) {
                const int col = col0 + wc * 64 + n * 16 + cl;
                float v = acc[m][n][j];
                if (EPI == 0) {
                    if (col < DINNER) ((float*)Cv)[(size_t)row * DINNER + col] = v;
                    else ((unsigned short*)C2v)[(size_t)row * DINNER + col - DINNER] = f2bf(v);
                } else if (EPI == 1) {
                    v += bias[col];
                    v = (v > 20.f) ? v : log1pf(__expf(v));
                    ((float*)Cv)[(size_t)row * ldc + col] = v * msk;
                } else if (EPI == 2) {
                    ((float*)Cv)[(size_t)row * ldc + col] =
                        residual[(size_t)row * ldc + col] + msk * v;
                } else {  // EPI 3
                    if (col < 64) aux[(size_t)row * 64 + col] = f2bf(v);
                    else if (col < 96) ((float*)Cv)[(size_t)row * 96 + col] = v;
                }
            }
        }
    }
}

// ---------------- causal depthwise conv (K=4) + SiLU + mask -> bf16 ----------------
// fully-masked blocks write exact zeros (no loads) so u == 0 at all masked rows
__global__ __launch_bounds__(256) void conv_silu_k(const float* __restrict__ ur,
                                                   const float* __restrict__ cw,
                                                   const int* __restrict__ lengths,
                                                   unsigned short* __restrict__ u) {
    const int g = blockIdx.x;              // NB * 512
    const int b = g >> 9;
    const int rem = g & 511;
    const int l0 = (rem >> 1) << 3;
    const int d4 = (rem & 1) * 1024 + threadIdx.x * 4;
    const int len = lengths[b];
    const size_t rb = (size_t)b * LSEQ;
    if (l0 >= len) {
        ushort4 z4 = {0, 0, 0, 0};
#pragma unroll
        for (int i = 0; i < 8; ++i)
            *(ushort4*)(u + (rb + l0 + i) * DINNER + d4) = z4;
        return;
    }
    float4 wq[4];
#pragma unroll
    for (int c = 0; c < 4; ++c) wq[c] = *(const float4*)(cw + 4 * (d4 + c));
    const float4 zero4 = {0.f, 0.f, 0.f, 0.f};
    float4 xm3 = (l0 - 3 >= 0 && l0 - 3 < len) ? *(const float4*)(ur + (rb + l0 - 3) * DINNER + d4) : zero4;
    float4 xm2 = (l0 - 2 >= 0 && l0 - 2 < len) ? *(const float4*)(ur + (rb + l0 - 2) * DINNER + d4) : zero4;
    float4 xm1 = (l0 - 1 >= 0 && l0 - 1 < len) ? *(const float4*)(ur + (rb + l0 - 1) * DINNER + d4) : zero4;
#pragma unroll
    for (int i = 0; i < 8; ++i) {
        const int l = l0 + i;
        const bool act = l < len;
        float4 x0 = act ? *(const float4*)(ur + (rb + l) * DINNER + d4) : zero4;
        float a0 = wq[0].x * xm3.x + wq[0].y * xm2.x + wq[0].z * xm1.x + wq[0].w * x0.x;
        float a1 = wq[1].x * xm3.y + wq[1].y * xm2.y + wq[1].z * xm1.y + wq[1].w * x0.y;
        float a2 = wq[2].x * xm3.z + wq[2].y * xm2.z + wq[2].z * xm1.z + wq[2].w * x0.z;
        float a3 = wq[3].x * xm3.w + wq[3].y * xm2.w + wq[3].z * xm1.w + wq[3].w * x0.w;
        ushort4 ov;
        ov.x = f2bf(act ? siluf(a0) : 0.f);
        ov.y = f2bf(act ? siluf(a1) : 0.f);
        ov.z = f2bf(act ? siluf(a2) : 0.f);
        ov.w = f2bf(act ? siluf(a3) : 0.f);
        *(ushort4*)(u + (rb + l) * DINNER + d4) = ov;
        xm3 = xm2; xm2 = xm1; xm1 = x0;
    }
}

// ---------------- scan phase 1: per-chunk local scan (h_in = 0) ----------------
__global__ __launch_bounds__(256) void scan_p1(const float* __restrict__ dlt,
                                               const unsigned short* __restrict__ uy,
                                               const float* __restrict__ xdbl,
                                               const float* __restrict__ A_log,
                                               const int* __restrict__ lengths,
                                               float* __restrict__ hloc,
                                               float* __restrict__ sumd) {
    __shared__ float2 sDU[TT][18];   // {delta, delta*u}; padded stride
    __shared__ float  sB[TT][20];
    const int t = threadIdx.x;
    const int s = blockIdx.x >> 9;
    const int bd = blockIdx.x & (NBD - 1);
    const int b = bd >> 7;
    const int d0 = (bd & 127) << 4;
    const int n = t & 15, ch = t >> 4;
    const size_t hidx = ((size_t)bd * SCH + s) * 256 + t;
    if (s * CH >= lengths[b]) {          // fully masked chunk: exact identity
        hloc[hidx] = 0.f;
        if (n == 0) sumd[(bd * SCH + s) * 16 + ch] = 0.f;
        return;
    }
    const int lr = t >> 2, lq = (t & 3) << 2;
    const int d = d0 + ch;
    const float Av2 = -__expf(A_log[d * NST + n]) * 1.44269504f;
    float h = 0.f, sd = 0.f;
    const size_t base = (size_t)b * LSEQ + (size_t)s * CH;

    for (int l0 = 0; l0 < CH; l0 += TT) {
        const size_t row = base + l0 + lr;
        float4 dv = *(const float4*)(dlt + row * DINNER + d0 + lq);
        ushort4 uv = *(const ushort4*)(uy + row * DINNER + d0 + lq);
        float4 bv = *(const float4*)(xdbl + row * 96 + 64 + lq);
        float4 w0 = {dv.x, dv.x * bf2f(uv.x), dv.y, dv.y * bf2f(uv.y)};
        float4 w1 = {dv.z, dv.z * bf2f(uv.z), dv.w, dv.w * bf2f(uv.w)};
        *(float4*)&sDU[lr][lq]     = w0;
        *(float4*)&sDU[lr][lq + 2] = w1;
        *(float4*)&sB[lr][lq] = bv;
        __syncthreads();
#pragma unroll 16
        for (int r = 0; r < TT; ++r) {
            float2 ddu = sDU[r][ch];
            float Bn = sB[r][n];
            float dA = __builtin_amdgcn_exp2f(ddu.x * Av2);
            h = fmaf(dA, h, ddu.y * Bn);
            sd += ddu.x;
        }
        __syncthreads();
    }
    hloc[hidx] = h;
    if (n == 0) sumd[(bd * SCH + s) * 16 + ch] = sd;
}

// ---------------- scan phase 2: sequential chunk fix-up + h_last ----------------
__global__ __launch_bounds__(256) void scan_p2(const float* __restrict__ hloc,
                                               const float* __restrict__ sumd,
                                               const float* __restrict__ A_log,
                                               float* __restrict__ hin,
                                               float* __restrict__ out_h) {
    const int t = threadIdx.x;
    const int bd = blockIdx.x;
    const int b = bd >> 7;
    const int d = ((bd & 127) << 4) + (t >> 4);
    const int n = t & 15;
    const float Av2 = -__expf(A_log[d * NST + n]) * 1.44269504f;
    float h = 0.f;
#pragma unroll
    for (int s = 0; s < SCH; ++s) {
        const size_t idx = ((size_t)bd * SCH + s) * 256 + t;
        hin[idx] = h;
        float P = __builtin_amdgcn_exp2f(Av2 * sumd[(bd * SCH + s) * 16 + (t >> 4)]);
        h = fmaf(P, h, hloc[idx]);
    }
    out_h[((size_t)(b * DINNER + d)) * NST + n] = h;
}

// ---------------- scan phase 3: replay chunk from h_in, produce gated y ----------------
__global__ __launch_bounds__(256) void scan_p3(const float* __restrict__ dlt,
                                               const unsigned short* __restrict__ zb,  // bf16 z
                                               unsigned short* uy,
                                               const float* __restrict__ xdbl,
                                               const float* __restrict__ A_log,
                                               const float* __restrict__ D_skip,
                                               const int* __restrict__ lengths,
                                               const float* __restrict__ hin) {
    __shared__ float2 sDU[TT][18];   // {delta, delta*u}
    __shared__ float2 sBC[TT][18];   // {B, C}
    __shared__ float  sY[TT][16];
    const int t = threadIdx.x;
    const int s = blockIdx.x >> 9;
    const int bd = blockIdx.x & (NBD - 1);
    const int b = bd >> 7;
    const int d0 = (bd & 127) << 4;
    if (s * CH >= lengths[b]) return;    // fully masked chunk: y never consumed
    const int lr = t >> 2, lq = (t & 3) << 2;
    const int ch = t >> 4, n = t & 15;
    const int d = d0 + ch;
    const float Av2 = -__expf(A_log[d * NST + n]) * 1.44269504f;
    const float4 Dv4 = *(const float4*)(D_skip + d0 + lq);
    float h = hin[((size_t)bd * SCH + s) * 256 + t];
    const size_t base = (size_t)b * LSEQ + (size_t)s * CH;

    for (int l0 = 0; l0 < CH; l0 += TT) {
        const size_t row = base + l0 + lr;
        float4 dv = *(const float4*)(dlt + row * DINNER + d0 + lq);
        ushort4 uv = *(const ushort4*)(uy + row * DINNER + d0 + lq);
        ushort4 zu = *(const ushort4*)(zb + row * DINNER + d0 + lq);
        float4 bv = *(const float4*)(xdbl + row * 96 + 64 + lq);
        float4 cv = *(const float4*)(xdbl + row * 96 + 80 + lq);
        const float uf0 = bf2f(uv.x), uf1 = bf2f(uv.y), uf2 = bf2f(uv.z), uf3 = bf2f(uv.w);
        float4 w0 = {dv.x, dv.x * uf0, dv.y, dv.y * uf1};
        float4 w1 = {dv.z, dv.z * uf2, dv.w, dv.w * uf3};
        *(float4*)&sDU[lr][lq]     = w0;
        *(float4*)&sDU[lr][lq + 2] = w1;
        float4 e0 = {bv.x, cv.x, bv.y, cv.y};
        float4 e1 = {bv.z, cv.z, bv.w, cv.w};
        *(float4*)&sBC[lr][lq]     = e0;
        *(float4*)&sBC[lr][lq + 2] = e1;
        __syncthreads();

#pragma unroll 16
        for (int r = 0; r < TT; ++r) {
            float2 ddu = sDU[r][ch];
            float2 bc  = sBC[r][n];
            float dA = __builtin_amdgcn_exp2f(ddu.x * Av2);
            h = fmaf(dA, h, ddu.y * bc.x);
            float p = h * bc.y;
            p += dpp_ror<0x128>(p);
            p += dpp_ror<0x124>(p);
            p += dpp_ror<0x122>(p);
            p += dpp_ror<0x121>(p);
            if (n == 0) sY[r][ch] = p;
        }
        __syncthreads();

        float4 yv = *(const float4*)&sY[lr][lq];
        ushort4 ov;
        ov.x = f2bf(fmaf(uf0, Dv4.x, yv.x) * siluf(bf2f(zu.x)));
        ov.y = f2bf(fmaf(uf1, Dv4.y, yv.y) * siluf(bf2f(zu.y)));
        ov.z = f2bf(fmaf(uf2, Dv4.z, yv.z) * siluf(bf2f(zu.z)));
        ov.w = f2bf(fmaf(uf3, Dv4.w, yv.w) * siluf(bf2f(zu.w)));
        *(ushort4*)(uy + row * DINNER + d0 + lq) = ov;
        __syncthreads();
    }
}

extern "C" void kernel_launch(void* const* d_in, const int* in_sizes, int n_in,
                              void* d_out, int out_size, void* d_ws, size_t ws_size,
                              hipStream_t stream) {
    const float* hs        = (const float*)d_in[0];
    const int*   lengths   = (const int*)d_in[1];
    const float* norm_w    = (const float*)d_in[2];
    const float* in_proj_w = (const float*)d_in[3];
    const float* conv_w    = (const float*)d_in[4];
    const float* x_proj_w  = (const float*)d_in[5];
    const float* dt_proj_w = (const float*)d_in[6];
    const float* dt_proj_b = (const float*)d_in[7];
    const float* A_log     = (const float*)d_in[8];
    const float* D_skip    = (const float*)d_in[9];
    const float* out_proj_w= (const float*)d_in[10];

    float* out = (float*)d_out;

    const int M = NB * LSEQ;                                            // 8192
    float* ur = (float*)d_ws;                                           // 8192x2048 f32 (64MB): u_raw -> dlt
    unsigned short* zb = (unsigned short*)(ur + (size_t)M * DINNER);    // 8192x2048 bf16 (32MB): z
    unsigned short* u_bf = zb + (size_t)M * DINNER;                     // 8192x2048 bf16 (32MB): u -> y
    float* xdbl = (float*)(u_bf + (size_t)M * DINNER);                  // 8192x96 f32 (3MB)
    unsigned short* w_in  = (unsigned short*)(xdbl + (size_t)M * 96);   // 4096x1024 (8MB)
    unsigned short* w_out = w_in + (size_t)4096 * 1024;                 // 1024x2048 (4MB)
    unsigned short* w_x   = w_out + (size_t)1024 * 2048;                // 96x2048
    unsigned short* w_dt  = w_x + (size_t)96 * 2048;                    // 2048x64
    unsigned short* dtr   = w_dt + (size_t)2048 * 64;                   // 8192x64 bf16 (1MB)
    float* hin            = (float*)(dtr + (size_t)M * 64);             // 512*16*256 f32 (8MB)
    unsigned short* xn_bf = u_bf;          // alias: dead once conv overwrites it
    float* dlt  = ur;                      // alias: ur dead after conv
    float* hloc = (float*)w_in;            // alias: w_in dead after in_proj (8MB exact)
    float* sumd = (float*)dtr;             // alias: dtr dead after dt_proj

    // 1. fused RMSNorm->bf16 + fused weight conversions (1 launch)
    rmsnorm_cvt_k<<<M, 256, 0, stream>>>(hs, norm_w, xn_bf);
    cvt_all_k<<<6464, 256, 0, stream>>>(in_proj_w, out_proj_w, x_proj_w, dt_proj_w,
                                        w_in, w_out, w_x, w_dt);

    // 2. in_proj (bf16 MFMA dbuf+swz, row-skip): ur f32 | z bf16  (8192x4096, K=1024)
    gemm_bf16<0><<<(4096 / 128) * (M / 128), 256, 0, stream>>>(
        xn_bf, DMODEL, w_in, DMODEL, ur, zb, DINNER, M, 4096, DMODEL, 4096 / 128,
        nullptr, nullptr, nullptr, lengths);

    // 3. causal depthwise conv + silu + mask -> u (bf16); masked blocks -> exact zeros
    conv_silu_k<<<NB * 512, 256, 0, stream>>>(ur, conv_w, lengths, u_bf);

    // 4. x_proj (bf16 MFMA dbuf+swz, row-skip): B,C -> xdbl f32; dt_r -> dtr bf16 (fused)
    gemm_bf16<3><<<1 * (M / 128), 256, 0, stream>>>(
        u_bf, DINNER, w_x, DINNER, xdbl, nullptr, 96, M, 96, DINNER, 1,
        nullptr, nullptr, dtr, lengths);

    // 5. dt_proj (bf16 MFMA+swz, row-skip) + softplus + mask -> delta f32 (over dead ur)
    gemm_bf16<1><<<(DINNER / 128) * (M / 128), 256, 0, stream>>>(
        dtr, 64, w_dt, 64, dlt, nullptr, DINNER, M, DINNER, 64, DINNER / 128,
        dt_proj_b, nullptr, nullptr, lengths);

    // 6. chunked selective scan (3 phases, chunk-skip); h_last -> tail of d_out
    {
        float* hlast = out + (size_t)M * DMODEL;
        scan_p1<<<NBD * SCH, 256, 0, stream>>>(dlt, u_bf, xdbl, A_log, lengths, hloc, sumd);
        scan_p2<<<NBD, 256, 0, stream>>>(hloc, sumd, A_log, hin, hlast);
        scan_p3<<<NBD * SCH, 256, 0, stream>>>(dlt, zb, u_bf, xdbl, A_log, D_skip, lengths, hin);
    }

    // 7. out_proj (bf16 MFMA dbuf+swz, row-skip -> residual copy) + residual + mask -> d_out
    gemm_bf16<2><<<(DMODEL / 128) * (M / 128), 256, 0, stream>>>(
        u_bf, DINNER, w_out, DINNER, out, nullptr, DMODEL, M, DMODEL, DINNER, DMODEL / 128,
        nullptr, hs, nullptr, lengths);
}